// Round 3
// baseline (856.230 us; speedup 1.0000x reference)
//
#include <hip/hip_runtime.h>

#define NEG_SLOPE 0.2f

// ---------------- GEMM: C[M,NCOLS] = A[M,128] @ B[128,NCOLS], fp32 ----------------
template<int NCOLS>
__global__ __launch_bounds__(256) void gemm_k128(const float* __restrict__ A,
    const float* __restrict__ B, float* __restrict__ C, int M) {
  constexpr int K = 128;
  constexpr int TM = 64;
  constexpr int XPAD = 68;                 // 272B row stride: 16B-aligned + bank spread
  __shared__ float xT[K][XPAD];            // A tile, transposed (k-major)
  __shared__ float Bs[K][NCOLS];           // entire B matrix (K=128 fixed)
  const int tid = threadIdx.x;
  const int m0 = blockIdx.x * TM;

  // stage B (whole matrix) via float4
  for (int i = tid; i < K * NCOLS / 4; i += 256) {
    const float4 v = reinterpret_cast<const float4*>(B)[i];
    const int k = (i * 4) / NCOLS, c = (i * 4) % NCOLS;
    *reinterpret_cast<float4*>(&Bs[k][c]) = v;
  }
  // stage A tile transposed
  for (int i = tid; i < TM * K / 4; i += 256) {
    const int m = (i * 4) / K, k = (i * 4) % K;
    float4 v = make_float4(0.f, 0.f, 0.f, 0.f);
    if (m0 + m < M) v = *reinterpret_cast<const float4*>(&A[(size_t)(m0 + m) * K + k]);
    xT[k + 0][m] = v.x; xT[k + 1][m] = v.y; xT[k + 2][m] = v.z; xT[k + 3][m] = v.w;
  }
  __syncthreads();

  constexpr int CW = NCOLS / 32;           // cols per thread: 4 (128) or 2 (64)
  const int c0 = (tid & 31) * CW;
  const int n0 = (tid >> 5) * 8;           // 8 node-groups x 8 nodes = 64
  float acc[8][CW];
  #pragma unroll
  for (int i = 0; i < 8; ++i)
    #pragma unroll
    for (int j = 0; j < CW; ++j) acc[i][j] = 0.f;

  #pragma unroll 2
  for (int k = 0; k < K; ++k) {
    float xv[8];
    *reinterpret_cast<float4*>(&xv[0]) = *reinterpret_cast<const float4*>(&xT[k][n0]);
    *reinterpret_cast<float4*>(&xv[4]) = *reinterpret_cast<const float4*>(&xT[k][n0 + 4]);
    float wv[CW];
    if constexpr (CW == 4)
      *reinterpret_cast<float4*>(&wv[0]) = *reinterpret_cast<const float4*>(&Bs[k][c0]);
    else
      *reinterpret_cast<float2*>(&wv[0]) = *reinterpret_cast<const float2*>(&Bs[k][c0]);
    #pragma unroll
    for (int i = 0; i < 8; ++i)
      #pragma unroll
      for (int j = 0; j < CW; ++j)
        acc[i][j] = fmaf(xv[i], wv[j], acc[i][j]);
  }

  #pragma unroll
  for (int i = 0; i < 8; ++i) {
    const int m = m0 + n0 + i;
    if (m < M) {
      if constexpr (CW == 4) {
        *reinterpret_cast<float4*>(&C[(size_t)m * NCOLS + c0]) =
            make_float4(acc[i][0], acc[i][1], acc[i][2], acc[i][3]);
      } else {
        *reinterpret_cast<float2*>(&C[(size_t)m * NCOLS + c0]) =
            make_float2(acc[i][0], acc[i][1]);
      }
    }
  }
}

// ---------------- el/er: per-(node,head) dot of hp row with attn vectors ----------------
template<int H, int F>
__global__ __launch_bounds__(256) void eler_kernel(const float* __restrict__ hp,
    const float* __restrict__ al, const float* __restrict__ ar,
    float* __restrict__ el, float* __restrict__ er, int NH) {
  const int idx = blockIdx.x * 256 + threadIdx.x;   // idx = n*H + h
  if (idx >= NH) return;
  const int h = idx % H;
  const float* __restrict__ row = hp + (size_t)idx * F;  // [N,H,F] flat => idx*F
  float sl = 0.f, sr = 0.f;
  #pragma unroll
  for (int f = 0; f < F; f += 4) {
    const float4 v = *reinterpret_cast<const float4*>(&row[f]);
    const float4 a = *reinterpret_cast<const float4*>(&al[h * F + f]);
    const float4 b = *reinterpret_cast<const float4*>(&ar[h * F + f]);
    sl += v.x * a.x + v.y * a.y + v.z * a.z + v.w * a.w;
    sr += v.x * b.x + v.y * b.y + v.z * b.z + v.w * b.w;
  }
  el[idx] = sl; er[idx] = sr;
}

// ---------------- edge scores: s = exp(leaky(el[src]+er[dst])), denom[dst] += s ----------------
template<int H>
__global__ __launch_bounds__(256) void score_kernel(const int* __restrict__ src,
    const int* __restrict__ dst, const float* __restrict__ el, const float* __restrict__ er,
    float* __restrict__ sbuf, float* denom, int nE) {
  const int e = blockIdx.x * 256 + threadIdx.x;
  if (e >= nE) return;
  const int s = src[e], d = dst[e];
  #pragma unroll
  for (int h = 0; h < H; ++h) {
    float v = el[s * H + h] + er[d * H + h];
    v = v > 0.f ? v : NEG_SLOPE * v;
    const float ex = __expf(v);
    sbuf[e * H + h] = ex;
    atomicAdd(&denom[d * H + h], ex);
  }
}

// ---------------- out init: out[n][c] = bias[c] ----------------
template<int C>
__global__ __launch_bounds__(256) void initout_kernel(const float* __restrict__ bias,
    float* __restrict__ out, int total) {
  const int idx = blockIdx.x * 256 + threadIdx.x;
  if (idx < total) out[idx] = bias[idx & (C - 1)];
}

// ---------------- aggregate: out[dst] += (s/denom[dst]) * hp[src], per (edge,col) ----------------
template<int H, int F>
__global__ __launch_bounds__(256) void agg_kernel(const int* __restrict__ src,
    const int* __restrict__ dst, const float* __restrict__ sbuf,
    const float* __restrict__ denom, const float* __restrict__ hp,
    float* out, int nE) {
  constexpr int HF = H * F;                // 128 or 64
  constexpr int EPB = 256 / HF;            // edges per block: 2 or 4
  const int e = blockIdx.x * EPB + threadIdx.x / HF;
  if (e >= nE) return;
  const int c = threadIdx.x & (HF - 1);
  const int s = src[e], d = dst[e];
  const int h = c / F;
  const float alpha = sbuf[e * H + h] / denom[d * H + h];
  atomicAdd(&out[(size_t)d * HF + c], alpha * hp[(size_t)s * HF + c]);
}

extern "C" void kernel_launch(void* const* d_in, const int* in_sizes, int n_in,
                              void* d_out, int out_size, void* d_ws, size_t ws_size,
                              hipStream_t stream) {
  const float* x   = (const float*)d_in[0];
  const float* W1  = (const float*)d_in[1];
  const float* al1 = (const float*)d_in[2];
  const float* ar1 = (const float*)d_in[3];
  const float* b1  = (const float*)d_in[4];
  const float* W2  = (const float*)d_in[5];
  const float* al2 = (const float*)d_in[6];
  const float* ar2 = (const float*)d_in[7];
  const float* b2  = (const float*)d_in[8];
  const int* src   = (const int*)d_in[9];
  const int* dst   = (const int*)d_in[10];
  const int N = in_sizes[0] / 128;
  const int E = in_sizes[9];
  float* out = (float*)d_out;

  // workspace layout (floats)
  float* ws     = (float*)d_ws;
  float* hp1    = ws;                          // N*128
  float* out1   = hp1 + (size_t)N * 128;       // N*128
  float* hp2    = out1 + (size_t)N * 128;      // N*64
  float* s1     = hp2 + (size_t)N * 64;        // E*4
  float* s2     = s1 + (size_t)E * 4;          // E
  float* el1    = s2 + E;                      // N*4
  float* er1    = el1 + (size_t)N * 4;         // N*4
  float* el2    = er1 + (size_t)N * 4;         // N
  float* er2    = el2 + N;                     // N
  float* denom1 = er2 + N;                     // N*4
  // denom2 = denom1 + N*4                     // N   (contiguous with denom1)
  float* denom2 = denom1 + (size_t)N * 4;

  // zero both denominators in one shot (contiguous N*5 floats)
  hipMemsetAsync(denom1, 0, (size_t)N * 5 * sizeof(float), stream);

  const dim3 blk(256);

  // ---- layer 1: D_IN=128 -> H=4, F=32 ----
  gemm_k128<128><<<dim3((N + 63) / 64), blk, 0, stream>>>(x, W1, hp1, N);
  eler_kernel<4, 32><<<dim3((N * 4 + 255) / 256), blk, 0, stream>>>(hp1, al1, ar1, el1, er1, N * 4);
  score_kernel<4><<<dim3((E + 255) / 256), blk, 0, stream>>>(src, dst, el1, er1, s1, denom1, E);
  initout_kernel<128><<<dim3((N * 128 + 255) / 256), blk, 0, stream>>>(b1, out1, N * 128);
  agg_kernel<4, 32><<<dim3((E + 1) / 2), blk, 0, stream>>>(src, dst, s1, denom1, hp1, out1, E);

  // ---- layer 2: 128 -> H=1, F=64 ----
  gemm_k128<64><<<dim3((N + 63) / 64), blk, 0, stream>>>(out1, W2, hp2, N);
  eler_kernel<1, 64><<<dim3((N + 255) / 256), blk, 0, stream>>>(hp2, al2, ar2, el2, er2, N);
  score_kernel<1><<<dim3((E + 255) / 256), blk, 0, stream>>>(src, dst, el2, er2, s2, denom2, E);
  initout_kernel<64><<<dim3((N * 64 + 255) / 256), blk, 0, stream>>>(b2, out, N * 64);
  agg_kernel<1, 64><<<dim3((E + 3) / 4), blk, 0, stream>>>(src, dst, s2, denom2, hp2, out, E);
}

// Round 4
// 428.571 us; speedup vs baseline: 1.9979x; 1.9979x over previous
//
#include <hip/hip_runtime.h>

#define NEG_SLOPE 0.2f

// ---------------- GEMM: C[M,NCOLS] = A[M,128] @ B[128,NCOLS], fp32 ----------------
template<int NCOLS>
__global__ __launch_bounds__(256) void gemm_k128(const float* __restrict__ A,
    const float* __restrict__ B, float* __restrict__ C, int M) {
  constexpr int K = 128;
  constexpr int TM = 64;
  constexpr int XPAD = 68;
  __shared__ float xT[K][XPAD];
  __shared__ float Bs[K][NCOLS];
  const int tid = threadIdx.x;
  const int m0 = blockIdx.x * TM;

  for (int i = tid; i < K * NCOLS / 4; i += 256) {
    const float4 v = reinterpret_cast<const float4*>(B)[i];
    const int k = (i * 4) / NCOLS, c = (i * 4) % NCOLS;
    *reinterpret_cast<float4*>(&Bs[k][c]) = v;
  }
  for (int i = tid; i < TM * K / 4; i += 256) {
    const int m = (i * 4) / K, k = (i * 4) % K;
    float4 v = make_float4(0.f, 0.f, 0.f, 0.f);
    if (m0 + m < M) v = *reinterpret_cast<const float4*>(&A[(size_t)(m0 + m) * K + k]);
    xT[k + 0][m] = v.x; xT[k + 1][m] = v.y; xT[k + 2][m] = v.z; xT[k + 3][m] = v.w;
  }
  __syncthreads();

  constexpr int CW = NCOLS / 32;
  const int c0 = (tid & 31) * CW;
  const int n0 = (tid >> 5) * 8;
  float acc[8][CW];
  #pragma unroll
  for (int i = 0; i < 8; ++i)
    #pragma unroll
    for (int j = 0; j < CW; ++j) acc[i][j] = 0.f;

  #pragma unroll 2
  for (int k = 0; k < K; ++k) {
    float xv[8];
    *reinterpret_cast<float4*>(&xv[0]) = *reinterpret_cast<const float4*>(&xT[k][n0]);
    *reinterpret_cast<float4*>(&xv[4]) = *reinterpret_cast<const float4*>(&xT[k][n0 + 4]);
    float wv[CW];
    if constexpr (CW == 4)
      *reinterpret_cast<float4*>(&wv[0]) = *reinterpret_cast<const float4*>(&Bs[k][c0]);
    else
      *reinterpret_cast<float2*>(&wv[0]) = *reinterpret_cast<const float2*>(&Bs[k][c0]);
    #pragma unroll
    for (int i = 0; i < 8; ++i)
      #pragma unroll
      for (int j = 0; j < CW; ++j)
        acc[i][j] = fmaf(xv[i], wv[j], acc[i][j]);
  }

  #pragma unroll
  for (int i = 0; i < 8; ++i) {
    const int m = m0 + n0 + i;
    if (m < M) {
      if constexpr (CW == 4) {
        *reinterpret_cast<float4*>(&C[(size_t)m * NCOLS + c0]) =
            make_float4(acc[i][0], acc[i][1], acc[i][2], acc[i][3]);
      } else {
        *reinterpret_cast<float2*>(&C[(size_t)m * NCOLS + c0]) =
            make_float2(acc[i][0], acc[i][1]);
      }
    }
  }
}

// ---------------- el/er ----------------
template<int H, int F>
__global__ __launch_bounds__(256) void eler_kernel(const float* __restrict__ hp,
    const float* __restrict__ al, const float* __restrict__ ar,
    float* __restrict__ el, float* __restrict__ er, int NH) {
  const int idx = blockIdx.x * 256 + threadIdx.x;
  if (idx >= NH) return;
  const int h = idx % H;
  const float* __restrict__ row = hp + (size_t)idx * F;
  float sl = 0.f, sr = 0.f;
  #pragma unroll
  for (int f = 0; f < F; f += 4) {
    const float4 v = *reinterpret_cast<const float4*>(&row[f]);
    const float4 a = *reinterpret_cast<const float4*>(&al[h * F + f]);
    const float4 b = *reinterpret_cast<const float4*>(&ar[h * F + f]);
    sl += v.x * a.x + v.y * a.y + v.z * a.z + v.w * a.w;
    sr += v.x * b.x + v.y * b.y + v.z * b.z + v.w * b.w;
  }
  el[idx] = sl; er[idx] = sr;
}

// ---------------- CSR build ----------------
__global__ __launch_bounds__(256) void hist_kernel(const int* __restrict__ dst,
    int* deg, int E) {
  const int e = blockIdx.x * 256 + threadIdx.x;
  if (e < E) atomicAdd(&deg[dst[e]], 1);
}

__global__ __launch_bounds__(1024) void scan_kernel(const int* __restrict__ deg,
    int* __restrict__ row_ptr, int* __restrict__ cursor, int N) {
  __shared__ int wsum[16];
  const int tid = threadIdx.x;
  const int lane = tid & 63, wid = tid >> 6;
  int carry = 0;
  for (int base = 0; base < N; base += 1024) {
    const int i = base + tid;
    const int v = (i < N) ? deg[i] : 0;
    int incl = v;
    #pragma unroll
    for (int off = 1; off < 64; off <<= 1) {
      const int t = __shfl_up(incl, off);
      if (lane >= off) incl += t;
    }
    if (lane == 63) wsum[wid] = incl;
    __syncthreads();
    int woff = 0;
    for (int w = 0; w < wid; ++w) woff += wsum[w];
    const int excl = carry + woff + incl - v;
    if (i < N) { row_ptr[i] = excl; cursor[i] = excl; }
    int tot = 0;
    for (int w = 0; w < 16; ++w) tot += wsum[w];
    carry += tot;
    __syncthreads();
  }
  if (tid == 0) row_ptr[N] = carry;
}

__global__ __launch_bounds__(256) void place_kernel(const int* __restrict__ src,
    const int* __restrict__ dst, int* cursor, int* __restrict__ csr_src, int E) {
  const int e = blockIdx.x * 256 + threadIdx.x;
  if (e < E) {
    const int pos = atomicAdd(&cursor[dst[e]], 1);
    csr_src[pos] = src[e];
  }
}

// ---------------- fused aggregate: one wave per dst node, no atomics ----------------
// out[d,:] = bias + (sum_e exp(leaky(el[src_e]+er[d])) * hp[src_e,:]) / sum_e exp(...)
template<int H, int F>
__global__ __launch_bounds__(256) void gat_agg(const int* __restrict__ row_ptr,
    const int* __restrict__ csr_src, const float* __restrict__ el,
    const float* __restrict__ er, const float* __restrict__ hp,
    const float* __restrict__ bias, float* __restrict__ out, int N) {
  constexpr int HF = H * F;
  constexpr int CPL = HF / 64;             // cols per lane: 2 (layer1) or 1 (layer2)
  const int wid = threadIdx.x >> 6;
  const int d = blockIdx.x * 4 + wid;
  if (d >= N) return;
  const int lane = threadIdx.x & 63;
  const int c0 = lane * CPL;
  const int h = c0 / F;
  const float erd = er[(size_t)d * H + h];
  const int beg = row_ptr[d], end = row_ptr[d + 1];
  float acc0 = 0.f, acc1 = 0.f, denom = 0.f;
  int s_cur = (beg < end) ? csr_src[beg] : 0;
  for (int i = beg; i < end; ++i) {
    const int s_next = (i + 1 < end) ? csr_src[i + 1] : 0;
    float v = el[(size_t)s_cur * H + h] + erd;
    v = v > 0.f ? v : NEG_SLOPE * v;
    const float ex = __expf(v);
    denom += ex;
    if constexpr (CPL == 2) {
      const float2 hv = *reinterpret_cast<const float2*>(&hp[(size_t)s_cur * HF + c0]);
      acc0 = fmaf(ex, hv.x, acc0);
      acc1 = fmaf(ex, hv.y, acc1);
    } else {
      acc0 = fmaf(ex, hp[(size_t)s_cur * HF + c0], acc0);
    }
    s_cur = s_next;
  }
  const float inv = denom > 0.f ? 1.f / denom : 0.f;   // deg==0 -> out = bias
  if constexpr (CPL == 2) {
    float2 o;
    o.x = bias[c0] + acc0 * inv;
    o.y = bias[c0 + 1] + acc1 * inv;
    *reinterpret_cast<float2*>(&out[(size_t)d * HF + c0]) = o;
  } else {
    out[(size_t)d * HF + c0] = bias[c0] + acc0 * inv;
  }
}

extern "C" void kernel_launch(void* const* d_in, const int* in_sizes, int n_in,
                              void* d_out, int out_size, void* d_ws, size_t ws_size,
                              hipStream_t stream) {
  const float* x   = (const float*)d_in[0];
  const float* W1  = (const float*)d_in[1];
  const float* al1 = (const float*)d_in[2];
  const float* ar1 = (const float*)d_in[3];
  const float* b1  = (const float*)d_in[4];
  const float* W2  = (const float*)d_in[5];
  const float* al2 = (const float*)d_in[6];
  const float* ar2 = (const float*)d_in[7];
  const float* b2  = (const float*)d_in[8];
  const int* src   = (const int*)d_in[9];
  const int* dst   = (const int*)d_in[10];
  const int N = in_sizes[0] / 128;
  const int E = in_sizes[9];
  float* out = (float*)d_out;

  // workspace layout
  float* ws   = (float*)d_ws;
  float* hp1  = ws;                          // N*128
  float* out1 = hp1 + (size_t)N * 128;       // N*128
  float* hp2  = out1 + (size_t)N * 128;      // N*64
  float* el1  = hp2 + (size_t)N * 64;        // N*4
  float* er1  = el1 + (size_t)N * 4;         // N*4
  float* el2  = er1 + (size_t)N * 4;         // N
  float* er2  = el2 + N;                     // N
  int* deg     = (int*)(er2 + N);            // N
  int* row_ptr = deg + N;                    // N+1
  int* cursor  = row_ptr + N + 1;            // N
  int* csr_src = cursor + N;                 // E

  const dim3 blk(256);

  // ---- CSR build (shared by both layers) ----
  hipMemsetAsync(deg, 0, (size_t)N * sizeof(int), stream);
  hist_kernel<<<dim3((E + 255) / 256), blk, 0, stream>>>(dst, deg, E);
  scan_kernel<<<dim3(1), dim3(1024), 0, stream>>>(deg, row_ptr, cursor, N);
  place_kernel<<<dim3((E + 255) / 256), blk, 0, stream>>>(src, dst, cursor, csr_src, E);

  // ---- layer 1: 128 -> H=4, F=32 ----
  gemm_k128<128><<<dim3((N + 63) / 64), blk, 0, stream>>>(x, W1, hp1, N);
  eler_kernel<4, 32><<<dim3((N * 4 + 255) / 256), blk, 0, stream>>>(hp1, al1, ar1, el1, er1, N * 4);
  gat_agg<4, 32><<<dim3((N + 3) / 4), blk, 0, stream>>>(row_ptr, csr_src, el1, er1, hp1, b1, out1, N);

  // ---- layer 2: 128 -> H=1, F=64 ----
  gemm_k128<64><<<dim3((N + 63) / 64), blk, 0, stream>>>(out1, W2, hp2, N);
  eler_kernel<1, 64><<<dim3((N + 255) / 256), blk, 0, stream>>>(hp2, al2, ar2, el2, er2, N);
  gat_agg<1, 64><<<dim3((N + 3) / 4), blk, 0, stream>>>(row_ptr, csr_src, el2, er2, hp2, b2, out, N);
}

// Round 6
// 315.687 us; speedup vs baseline: 2.7123x; 1.3576x over previous
//
#include <hip/hip_runtime.h>

#define NEG_SLOPE 0.2f

// ---------------- GEMM: C[M,NCOLS] = A[M,128] @ B[128,NCOLS], fp32 ----------------
// A tile staged row-major in LDS (32 KB -> 5 blocks/CU); B read direct from
// global (64/32 KB, L1/L2-resident, one coalesced 512B line per wave per k).
template<int NCOLS>
__global__ __launch_bounds__(256) void gemm_k128(const float* __restrict__ A,
    const float* __restrict__ B, float* __restrict__ C, int M) {
  constexpr int K = 128;
  constexpr int TM = 64;
  __shared__ float As[TM][K];              // 32 KB, row-major
  const int tid = threadIdx.x;
  const int m0 = blockIdx.x * TM;

  // stage A tile (coalesced global float4, conflict-free ds_write_b128)
  for (int i = tid; i < TM * K / 4; i += 256) {
    const int m = (i * 4) / K, k = (i * 4) % K;
    float4 v = make_float4(0.f, 0.f, 0.f, 0.f);
    if (m0 + m < M) v = *reinterpret_cast<const float4*>(&A[(size_t)(m0 + m) * K + k]);
    *reinterpret_cast<float4*>(&As[m][k]) = v;
  }
  __syncthreads();

  constexpr int CW = NCOLS / 32;           // cols per thread: 4 (128) or 2 (64)
  const int c0 = (tid & 31) * CW;
  const int n0 = (tid >> 5) * 8;           // 8 node-groups x 8 nodes = 64
  float acc[8][CW];
  #pragma unroll
  for (int i = 0; i < 8; ++i)
    #pragma unroll
    for (int j = 0; j < CW; ++j) acc[i][j] = 0.f;

  #pragma unroll 4
  for (int k = 0; k < K; ++k) {
    float wv[CW];
    if constexpr (CW == 4)
      *reinterpret_cast<float4*>(&wv[0]) = *reinterpret_cast<const float4*>(&B[(size_t)k * NCOLS + c0]);
    else
      *reinterpret_cast<float2*>(&wv[0]) = *reinterpret_cast<const float2*>(&B[(size_t)k * NCOLS + c0]);
    float xv[8];
    #pragma unroll
    for (int i = 0; i < 8; ++i) xv[i] = As[n0 + i][k];   // broadcast ds_read_b32
    #pragma unroll
    for (int i = 0; i < 8; ++i)
      #pragma unroll
      for (int j = 0; j < CW; ++j)
        acc[i][j] = fmaf(xv[i], wv[j], acc[i][j]);
  }

  #pragma unroll
  for (int i = 0; i < 8; ++i) {
    const int m = m0 + n0 + i;
    if (m < M) {
      if constexpr (CW == 4) {
        *reinterpret_cast<float4*>(&C[(size_t)m * NCOLS + c0]) =
            make_float4(acc[i][0], acc[i][1], acc[i][2], acc[i][3]);
      } else {
        *reinterpret_cast<float2*>(&C[(size_t)m * NCOLS + c0]) =
            make_float2(acc[i][0], acc[i][1]);
      }
    }
  }
}

// ---------------- el/er ----------------
template<int H, int F>
__global__ __launch_bounds__(256) void eler_kernel(const float* __restrict__ hp,
    const float* __restrict__ al, const float* __restrict__ ar,
    float* __restrict__ el, float* __restrict__ er, int NH) {
  const int idx = blockIdx.x * 256 + threadIdx.x;
  if (idx >= NH) return;
  const int h = idx % H;
  const float* __restrict__ row = hp + (size_t)idx * F;
  float sl = 0.f, sr = 0.f;
  #pragma unroll
  for (int f = 0; f < F; f += 4) {
    const float4 v = *reinterpret_cast<const float4*>(&row[f]);
    const float4 a = *reinterpret_cast<const float4*>(&al[h * F + f]);
    const float4 b = *reinterpret_cast<const float4*>(&ar[h * F + f]);
    sl += v.x * a.x + v.y * a.y + v.z * a.z + v.w * a.w;
    sr += v.x * b.x + v.y * b.y + v.z * b.z + v.w * b.w;
  }
  el[idx] = sl; er[idx] = sr;
}

// ---------------- CSR build ----------------
__global__ __launch_bounds__(256) void hist_kernel(const int* __restrict__ dst,
    int* deg, int E) {
  const int e = blockIdx.x * 256 + threadIdx.x;
  if (e < E) atomicAdd(&deg[dst[e]], 1);
}

__global__ __launch_bounds__(1024) void scan_kernel(const int* __restrict__ deg,
    int* __restrict__ row_ptr, int* __restrict__ cursor, int N) {
  __shared__ int wsum[16];
  const int tid = threadIdx.x;
  const int lane = tid & 63, wid = tid >> 6;
  int carry = 0;
  for (int base = 0; base < N; base += 1024) {
    const int i = base + tid;
    const int v = (i < N) ? deg[i] : 0;
    int incl = v;
    #pragma unroll
    for (int off = 1; off < 64; off <<= 1) {
      const int t = __shfl_up(incl, off);
      if (lane >= off) incl += t;
    }
    if (lane == 63) wsum[wid] = incl;
    __syncthreads();
    int woff = 0;
    for (int w = 0; w < wid; ++w) woff += wsum[w];
    const int excl = carry + woff + incl - v;
    if (i < N) { row_ptr[i] = excl; cursor[i] = excl; }
    int tot = 0;
    for (int w = 0; w < 16; ++w) tot += wsum[w];
    carry += tot;
    __syncthreads();
  }
  if (tid == 0) row_ptr[N] = carry;
}

__global__ __launch_bounds__(256) void place_kernel(const int* __restrict__ src,
    const int* __restrict__ dst, int* cursor, int* __restrict__ csr_src, int E) {
  const int e = blockIdx.x * 256 + threadIdx.x;
  if (e < E) {
    const int pos = atomicAdd(&cursor[dst[e]], 1);
    csr_src[pos] = src[e];
  }
}

// ---------------- fused aggregate: one wave per dst node, 4-edge batches ----------------
template<int H, int F>
__global__ __launch_bounds__(256) void gat_agg(const int* __restrict__ row_ptr,
    const int* __restrict__ csr_src, const float* __restrict__ el,
    const float* __restrict__ er, const float* __restrict__ hp,
    const float* __restrict__ bias, float* __restrict__ out, int N) {
  constexpr int HF = H * F;
  constexpr int CPL = HF / 64;             // cols per lane: 2 (layer1) or 1 (layer2)
  const int wid = threadIdx.x >> 6;
  const int d = blockIdx.x * 4 + wid;
  if (d >= N) return;
  const int lane = threadIdx.x & 63;
  const int c0 = lane * CPL;
  const int h = c0 / F;
  const float erd = er[(size_t)d * H + h];
  const int beg = row_ptr[d], end = row_ptr[d + 1];
  float a0 = 0.f, a1 = 0.f, denom = 0.f;
  int i = beg;
  // 4-edge batches: 4 independent el+hp load chains in flight
  for (; i + 4 <= end; i += 4) {
    const int s0 = csr_src[i + 0], s1 = csr_src[i + 1],
              s2 = csr_src[i + 2], s3 = csr_src[i + 3];
    const float e0 = el[(size_t)s0 * H + h], e1 = el[(size_t)s1 * H + h],
                e2 = el[(size_t)s2 * H + h], e3 = el[(size_t)s3 * H + h];
    if constexpr (CPL == 2) {
      const float2 v0 = *reinterpret_cast<const float2*>(&hp[(size_t)s0 * HF + c0]);
      const float2 v1 = *reinterpret_cast<const float2*>(&hp[(size_t)s1 * HF + c0]);
      const float2 v2 = *reinterpret_cast<const float2*>(&hp[(size_t)s2 * HF + c0]);
      const float2 v3 = *reinterpret_cast<const float2*>(&hp[(size_t)s3 * HF + c0]);
      float t0 = e0 + erd; t0 = t0 > 0.f ? t0 : NEG_SLOPE * t0;
      float t1 = e1 + erd; t1 = t1 > 0.f ? t1 : NEG_SLOPE * t1;
      float t2 = e2 + erd; t2 = t2 > 0.f ? t2 : NEG_SLOPE * t2;
      float t3 = e3 + erd; t3 = t3 > 0.f ? t3 : NEG_SLOPE * t3;
      const float x0 = __expf(t0), x1 = __expf(t1), x2 = __expf(t2), x3 = __expf(t3);
      denom += (x0 + x1) + (x2 + x3);
      a0 = fmaf(x0, v0.x, a0); a1 = fmaf(x0, v0.y, a1);
      a0 = fmaf(x1, v1.x, a0); a1 = fmaf(x1, v1.y, a1);
      a0 = fmaf(x2, v2.x, a0); a1 = fmaf(x2, v2.y, a1);
      a0 = fmaf(x3, v3.x, a0); a1 = fmaf(x3, v3.y, a1);
    } else {
      const float v0 = hp[(size_t)s0 * HF + c0];
      const float v1 = hp[(size_t)s1 * HF + c0];
      const float v2 = hp[(size_t)s2 * HF + c0];
      const float v3 = hp[(size_t)s3 * HF + c0];
      float t0 = e0 + erd; t0 = t0 > 0.f ? t0 : NEG_SLOPE * t0;
      float t1 = e1 + erd; t1 = t1 > 0.f ? t1 : NEG_SLOPE * t1;
      float t2 = e2 + erd; t2 = t2 > 0.f ? t2 : NEG_SLOPE * t2;
      float t3 = e3 + erd; t3 = t3 > 0.f ? t3 : NEG_SLOPE * t3;
      const float x0 = __expf(t0), x1 = __expf(t1), x2 = __expf(t2), x3 = __expf(t3);
      denom += (x0 + x1) + (x2 + x3);
      a0 = fmaf(x0, v0, a0); a0 = fmaf(x1, v1, a0);
      a0 = fmaf(x2, v2, a0); a0 = fmaf(x3, v3, a0);
    }
  }
  for (; i < end; ++i) {
    const int s = csr_src[i];
    float t = el[(size_t)s * H + h] + erd;
    t = t > 0.f ? t : NEG_SLOPE * t;
    const float ex = __expf(t);
    denom += ex;
    if constexpr (CPL == 2) {
      const float2 v = *reinterpret_cast<const float2*>(&hp[(size_t)s * HF + c0]);
      a0 = fmaf(ex, v.x, a0); a1 = fmaf(ex, v.y, a1);
    } else {
      a0 = fmaf(ex, hp[(size_t)s * HF + c0], a0);
    }
  }
  const float inv = denom > 0.f ? 1.f / denom : 0.f;   // deg==0 -> out = bias
  if constexpr (CPL == 2) {
    float2 o;
    o.x = bias[c0] + a0 * inv;
    o.y = bias[c0 + 1] + a1 * inv;
    *reinterpret_cast<float2*>(&out[(size_t)d * HF + c0]) = o;
  } else {
    out[(size_t)d * HF + c0] = bias[c0] + a0 * inv;
  }
}

extern "C" void kernel_launch(void* const* d_in, const int* in_sizes, int n_in,
                              void* d_out, int out_size, void* d_ws, size_t ws_size,
                              hipStream_t stream) {
  const float* x   = (const float*)d_in[0];
  const float* W1  = (const float*)d_in[1];
  const float* al1 = (const float*)d_in[2];
  const float* ar1 = (const float*)d_in[3];
  const float* b1  = (const float*)d_in[4];
  const float* W2  = (const float*)d_in[5];
  const float* al2 = (const float*)d_in[6];
  const float* ar2 = (const float*)d_in[7];
  const float* b2  = (const float*)d_in[8];
  const int* src   = (const int*)d_in[9];
  const int* dst   = (const int*)d_in[10];
  const int N = in_sizes[0] / 128;
  const int E = in_sizes[9];
  float* out = (float*)d_out;

  // workspace layout
  float* ws   = (float*)d_ws;
  float* hp1  = ws;                          // N*128
  float* out1 = hp1 + (size_t)N * 128;       // N*128
  float* hp2  = out1 + (size_t)N * 128;      // N*64
  float* el1  = hp2 + (size_t)N * 64;        // N*4
  float* er1  = el1 + (size_t)N * 4;         // N*4
  float* el2  = er1 + (size_t)N * 4;         // N
  float* er2  = el2 + N;                     // N
  int* deg     = (int*)(er2 + N);            // N
  int* row_ptr = deg + N;                    // N+1
  int* cursor  = row_ptr + N + 1;            // N
  int* csr_src = cursor + N;                 // E

  const dim3 blk(256);

  // ---- CSR build (shared by both layers) ----
  hipMemsetAsync(deg, 0, (size_t)N * sizeof(int), stream);
  hist_kernel<<<dim3((E + 255) / 256), blk, 0, stream>>>(dst, deg, E);
  scan_kernel<<<dim3(1), dim3(1024), 0, stream>>>(deg, row_ptr, cursor, N);
  place_kernel<<<dim3((E + 255) / 256), blk, 0, stream>>>(src, dst, cursor, csr_src, E);

  // ---- layer 1: 128 -> H=4, F=32 ----
  gemm_k128<128><<<dim3((N + 63) / 64), blk, 0, stream>>>(x, W1, hp1, N);
  eler_kernel<4, 32><<<dim3((N * 4 + 255) / 256), blk, 0, stream>>>(hp1, al1, ar1, el1, er1, N * 4);
  gat_agg<4, 32><<<dim3((N + 3) / 4), blk, 0, stream>>>(row_ptr, csr_src, el1, er1, hp1, b1, out1, N);

  // ---- layer 2: 128 -> H=1, F=64 ----
  gemm_k128<64><<<dim3((N + 63) / 64), blk, 0, stream>>>(out1, W2, hp2, N);
  eler_kernel<1, 64><<<dim3((N + 255) / 256), blk, 0, stream>>>(hp2, al2, ar2, el2, er2, N);
  gat_agg<1, 64><<<dim3((N + 3) / 4), blk, 0, stream>>>(row_ptr, csr_src, el2, er2, hp2, b2, out, N);
}

// Round 7
// 248.869 us; speedup vs baseline: 3.4405x; 1.2685x over previous
//
#include <hip/hip_runtime.h>

#define NEG_SLOPE 0.2f

// ------------- GEMM + fused el/er: C=A@B, el/er via in-register reduce -------------
// A tile row-major in LDS (32 KB -> high occupancy); B direct from global
// (64/32 KB, L1/L2-resident). Epilogue: el[m,h]=sum_f al[h,f]*C[m,h*F+f] via
// shfl_xor reduce over the lanes owning that head's columns.
template<int NCOLS, int H>
__global__ __launch_bounds__(256) void gemm_eler(const float* __restrict__ A,
    const float* __restrict__ B, const float* __restrict__ al, const float* __restrict__ ar,
    float* __restrict__ C, float* __restrict__ el, float* __restrict__ er, int M) {
  constexpr int K = 128;
  constexpr int TM = 64;
  constexpr int F = NCOLS / H;
  __shared__ float As[TM][K];              // 32 KB
  const int tid = threadIdx.x;
  const int m0 = blockIdx.x * TM;

  for (int i = tid; i < TM * K / 4; i += 256) {
    const int m = (i * 4) / K, k = (i * 4) % K;
    float4 v = make_float4(0.f, 0.f, 0.f, 0.f);
    if (m0 + m < M) v = *reinterpret_cast<const float4*>(&A[(size_t)(m0 + m) * K + k]);
    *reinterpret_cast<float4*>(&As[m][k]) = v;
  }
  __syncthreads();

  constexpr int CW = NCOLS / 32;           // cols per thread: 4 or 2
  const int c0 = (tid & 31) * CW;
  const int n0 = (tid >> 5) * 8;
  float acc[8][CW];
  #pragma unroll
  for (int i = 0; i < 8; ++i)
    #pragma unroll
    for (int j = 0; j < CW; ++j) acc[i][j] = 0.f;

  #pragma unroll 4
  for (int k = 0; k < K; ++k) {
    float wv[CW];
    if constexpr (CW == 4)
      *reinterpret_cast<float4*>(&wv[0]) = *reinterpret_cast<const float4*>(&B[(size_t)k * NCOLS + c0]);
    else
      *reinterpret_cast<float2*>(&wv[0]) = *reinterpret_cast<const float2*>(&B[(size_t)k * NCOLS + c0]);
    float xv[8];
    #pragma unroll
    for (int i = 0; i < 8; ++i) xv[i] = As[n0 + i][k];
    #pragma unroll
    for (int i = 0; i < 8; ++i)
      #pragma unroll
      for (int j = 0; j < CW; ++j)
        acc[i][j] = fmaf(xv[i], wv[j], acc[i][j]);
  }

  // attn vectors for this thread's columns (flat index == c0+j)
  float alv[CW], arv[CW];
  if constexpr (CW == 4) {
    *reinterpret_cast<float4*>(&alv[0]) = *reinterpret_cast<const float4*>(&al[c0]);
    *reinterpret_cast<float4*>(&arv[0]) = *reinterpret_cast<const float4*>(&ar[c0]);
  } else {
    *reinterpret_cast<float2*>(&alv[0]) = *reinterpret_cast<const float2*>(&al[c0]);
    *reinterpret_cast<float2*>(&arv[0]) = *reinterpret_cast<const float2*>(&ar[c0]);
  }
  constexpr int GRP = F / CW;              // lanes per head group: 8 (L1) or 32 (L2)
  const int h = c0 / F;

  #pragma unroll
  for (int i = 0; i < 8; ++i) {
    const int m = m0 + n0 + i;
    // C store
    if (m < M) {
      if constexpr (CW == 4)
        *reinterpret_cast<float4*>(&C[(size_t)m * NCOLS + c0]) =
            make_float4(acc[i][0], acc[i][1], acc[i][2], acc[i][3]);
      else
        *reinterpret_cast<float2*>(&C[(size_t)m * NCOLS + c0]) =
            make_float2(acc[i][0], acc[i][1]);
    }
    // fused el/er
    float pl = 0.f, pr = 0.f;
    #pragma unroll
    for (int j = 0; j < CW; ++j) {
      pl = fmaf(alv[j], acc[i][j], pl);
      pr = fmaf(arv[j], acc[i][j], pr);
    }
    #pragma unroll
    for (int off = 1; off < GRP; off <<= 1) {
      pl += __shfl_xor(pl, off);
      pr += __shfl_xor(pr, off);
    }
    if (((tid & 31) & (GRP - 1)) == 0 && m < M) {
      el[(size_t)m * H + h] = pl;
      er[(size_t)m * H + h] = pr;
    }
  }
}

// ---------------- CSR build ----------------
__global__ __launch_bounds__(256) void hist_kernel(const int* __restrict__ dst,
    int* deg, int E) {
  const int e = blockIdx.x * 256 + threadIdx.x;
  if (e < E) atomicAdd(&deg[dst[e]], 1);
}

// 3-phase scan: block sums -> scan partials (1 wave) -> per-block scan + offset
__global__ __launch_bounds__(256) void block_sum_kernel(const int* __restrict__ deg,
    int* __restrict__ partials, int N) {
  __shared__ int wsum[4];
  const int tid = threadIdx.x;
  const int base = blockIdx.x * 1024 + tid * 4;
  int s = 0;
  #pragma unroll
  for (int j = 0; j < 4; ++j) if (base + j < N) s += deg[base + j];
  #pragma unroll
  for (int off = 32; off >= 1; off >>= 1) s += __shfl_down(s, off);
  if ((tid & 63) == 0) wsum[tid >> 6] = s;
  __syncthreads();
  if (tid == 0) partials[blockIdx.x] = wsum[0] + wsum[1] + wsum[2] + wsum[3];
}

__global__ __launch_bounds__(64) void scan_partials_kernel(int* partials, int nb) {
  const int tid = threadIdx.x;
  int v = (tid < nb) ? partials[tid] : 0;
  int incl = v;
  #pragma unroll
  for (int off = 1; off < 64; off <<= 1) {
    const int t = __shfl_up(incl, off);
    if (tid >= off) incl += t;
  }
  if (tid < nb) partials[tid] = incl - v;   // exclusive
}

__global__ __launch_bounds__(256) void block_scan_kernel(const int* __restrict__ deg,
    const int* __restrict__ partials, int* __restrict__ row_ptr,
    int* __restrict__ cursor, int N, int E) {
  __shared__ int wtot[4];
  const int tid = threadIdx.x;
  const int lane = tid & 63, wid = tid >> 6;
  const int idx = blockIdx.x * 1024 + tid * 4;
  int v[4];
  #pragma unroll
  for (int j = 0; j < 4; ++j) v[j] = (idx + j < N) ? deg[idx + j] : 0;
  const int tsum = v[0] + v[1] + v[2] + v[3];
  int incl = tsum;
  #pragma unroll
  for (int off = 1; off < 64; off <<= 1) {
    const int t = __shfl_up(incl, off);
    if (lane >= off) incl += t;
  }
  if (lane == 63) wtot[wid] = incl;
  __syncthreads();
  int excl = partials[blockIdx.x] + incl - tsum;
  for (int w = 0; w < wid; ++w) excl += wtot[w];
  #pragma unroll
  for (int j = 0; j < 4; ++j) {
    if (idx + j < N) { row_ptr[idx + j] = excl; cursor[idx + j] = excl; excl += v[j]; }
  }
  if (blockIdx.x == 0 && tid == 0) row_ptr[N] = E;
}

__global__ __launch_bounds__(256) void place_kernel(const int* __restrict__ src,
    const int* __restrict__ dst, int* cursor, int* __restrict__ csr_src, int E) {
  const int e = blockIdx.x * 256 + threadIdx.x;
  if (e < E) {
    const int pos = atomicAdd(&cursor[dst[e]], 1);
    csr_src[pos] = src[e];
  }
}

// ---------------- fused aggregate: one wave per dst node, 8-edge batches ----------------
template<int H, int F>
__global__ __launch_bounds__(256) void gat_agg(const int* __restrict__ row_ptr,
    const int* __restrict__ csr_src, const float* __restrict__ el,
    const float* __restrict__ er, const float* __restrict__ hp,
    const float* __restrict__ bias, float* __restrict__ out, int N) {
  constexpr int HF = H * F;
  constexpr int CPL = HF / 64;             // 2 (layer1) or 1 (layer2)
  const int wid = threadIdx.x >> 6;
  const int d = blockIdx.x * 4 + wid;
  if (d >= N) return;
  const int lane = threadIdx.x & 63;
  const int c0 = lane * CPL;
  const int h = c0 / F;
  const float erd = er[(size_t)d * H + h];
  const int beg = row_ptr[d], end = row_ptr[d + 1];
  float a0 = 0.f, a1 = 0.f, denom = 0.f;
  int i = beg;

  // 8-edge batches: 8 independent el+hp chains in flight
  for (; i + 8 <= end; i += 8) {
    int s[8];
    #pragma unroll
    for (int j = 0; j < 8; ++j) s[j] = csr_src[i + j];
    float ee[8];
    #pragma unroll
    for (int j = 0; j < 8; ++j) ee[j] = el[(size_t)s[j] * H + h];
    if constexpr (CPL == 2) {
      float2 v[8];
      #pragma unroll
      for (int j = 0; j < 8; ++j)
        v[j] = *reinterpret_cast<const float2*>(&hp[(size_t)s[j] * HF + c0]);
      #pragma unroll
      for (int j = 0; j < 8; ++j) {
        float t = ee[j] + erd; t = t > 0.f ? t : NEG_SLOPE * t;
        const float x = __expf(t);
        denom += x;
        a0 = fmaf(x, v[j].x, a0); a1 = fmaf(x, v[j].y, a1);
      }
    } else {
      float v[8];
      #pragma unroll
      for (int j = 0; j < 8; ++j) v[j] = hp[(size_t)s[j] * HF + c0];
      #pragma unroll
      for (int j = 0; j < 8; ++j) {
        float t = ee[j] + erd; t = t > 0.f ? t : NEG_SLOPE * t;
        const float x = __expf(t);
        denom += x;
        a0 = fmaf(x, v[j], a0);
      }
    }
  }
  // 4-edge batch
  for (; i + 4 <= end; i += 4) {
    int s[4];
    #pragma unroll
    for (int j = 0; j < 4; ++j) s[j] = csr_src[i + j];
    float ee[4];
    #pragma unroll
    for (int j = 0; j < 4; ++j) ee[j] = el[(size_t)s[j] * H + h];
    if constexpr (CPL == 2) {
      float2 v[4];
      #pragma unroll
      for (int j = 0; j < 4; ++j)
        v[j] = *reinterpret_cast<const float2*>(&hp[(size_t)s[j] * HF + c0]);
      #pragma unroll
      for (int j = 0; j < 4; ++j) {
        float t = ee[j] + erd; t = t > 0.f ? t : NEG_SLOPE * t;
        const float x = __expf(t);
        denom += x;
        a0 = fmaf(x, v[j].x, a0); a1 = fmaf(x, v[j].y, a1);
      }
    } else {
      float v[4];
      #pragma unroll
      for (int j = 0; j < 4; ++j) v[j] = hp[(size_t)s[j] * HF + c0];
      #pragma unroll
      for (int j = 0; j < 4; ++j) {
        float t = ee[j] + erd; t = t > 0.f ? t : NEG_SLOPE * t;
        const float x = __expf(t);
        denom += x;
        a0 = fmaf(x, v[j], a0);
      }
    }
  }
  // tail
  for (; i < end; ++i) {
    const int s = csr_src[i];
    float t = el[(size_t)s * H + h] + erd;
    t = t > 0.f ? t : NEG_SLOPE * t;
    const float x = __expf(t);
    denom += x;
    if constexpr (CPL == 2) {
      const float2 v = *reinterpret_cast<const float2*>(&hp[(size_t)s * HF + c0]);
      a0 = fmaf(x, v.x, a0); a1 = fmaf(x, v.y, a1);
    } else {
      a0 = fmaf(x, hp[(size_t)s * HF + c0], a0);
    }
  }

  const float inv = denom > 0.f ? 1.f / denom : 0.f;   // deg==0 -> out = bias
  if constexpr (CPL == 2) {
    float2 o;
    o.x = bias[c0] + a0 * inv;
    o.y = bias[c0 + 1] + a1 * inv;
    *reinterpret_cast<float2*>(&out[(size_t)d * HF + c0]) = o;
  } else {
    out[(size_t)d * HF + c0] = bias[c0] + a0 * inv;
  }
}

extern "C" void kernel_launch(void* const* d_in, const int* in_sizes, int n_in,
                              void* d_out, int out_size, void* d_ws, size_t ws_size,
                              hipStream_t stream) {
  const float* x   = (const float*)d_in[0];
  const float* W1  = (const float*)d_in[1];
  const float* al1 = (const float*)d_in[2];
  const float* ar1 = (const float*)d_in[3];
  const float* b1  = (const float*)d_in[4];
  const float* W2  = (const float*)d_in[5];
  const float* al2 = (const float*)d_in[6];
  const float* ar2 = (const float*)d_in[7];
  const float* b2  = (const float*)d_in[8];
  const int* src   = (const int*)d_in[9];
  const int* dst   = (const int*)d_in[10];
  const int N = in_sizes[0] / 128;
  const int E = in_sizes[9];
  float* out = (float*)d_out;

  // workspace layout
  float* ws   = (float*)d_ws;
  float* hp1  = ws;                          // N*128
  float* out1 = hp1 + (size_t)N * 128;       // N*128
  float* hp2  = out1 + (size_t)N * 128;      // N*64
  float* el1  = hp2 + (size_t)N * 64;        // N*4
  float* er1  = el1 + (size_t)N * 4;         // N*4
  float* el2  = er1 + (size_t)N * 4;         // N
  float* er2  = el2 + N;                     // N
  int* deg     = (int*)(er2 + N);            // N
  int* row_ptr = deg + N;                    // N+1
  int* cursor  = row_ptr + N + 1;            // N
  int* csr_src = cursor + N;                 // E
  int* partials = csr_src + E;               // ~N/1024 + 1

  const dim3 blk(256);
  const int nb = (N + 1023) / 1024;

  // ---- CSR build (shared by both layers) ----
  hipMemsetAsync(deg, 0, (size_t)N * sizeof(int), stream);
  hist_kernel<<<dim3((E + 255) / 256), blk, 0, stream>>>(dst, deg, E);
  block_sum_kernel<<<dim3(nb), blk, 0, stream>>>(deg, partials, N);
  scan_partials_kernel<<<dim3(1), dim3(64), 0, stream>>>(partials, nb);
  block_scan_kernel<<<dim3(nb), blk, 0, stream>>>(deg, partials, row_ptr, cursor, N, E);
  place_kernel<<<dim3((E + 255) / 256), blk, 0, stream>>>(src, dst, cursor, csr_src, E);

  // ---- layer 1: 128 -> H=4, F=32 ----
  gemm_eler<128, 4><<<dim3((N + 63) / 64), blk, 0, stream>>>(x, W1, al1, ar1, hp1, el1, er1, N);
  gat_agg<4, 32><<<dim3((N + 3) / 4), blk, 0, stream>>>(row_ptr, csr_src, el1, er1, hp1, b1, out1, N);

  // ---- layer 2: 128 -> H=1, F=64 ----
  gemm_eler<64, 1><<<dim3((N + 63) / 64), blk, 0, stream>>>(out1, W2, al2, ar2, hp2, el2, er2, N);
  gat_agg<1, 64><<<dim3((N + 3) / 4), blk, 0, stream>>>(row_ptr, csr_src, el2, er2, hp2, b2, out, N);
}

// Round 9
// 236.868 us; speedup vs baseline: 3.6148x; 1.0507x over previous
//
#include <hip/hip_runtime.h>

#define NEG_SLOPE 0.2f

// float -> bf16 bits, round-to-nearest-even (finite inputs)
static __device__ __forceinline__ unsigned short f2bf(float f) {
  unsigned x = __float_as_uint(f);
  return (unsigned short)((x + 0x7FFFu + ((x >> 16) & 1u)) >> 16);
}
static __device__ __forceinline__ float bf2f(unsigned short u) {
  return __uint_as_float((unsigned)u << 16);
}

// ------------- GEMM + fused el/er + bf16 feature emit -------------
// C=A@B kept in registers; emits bf16 row copy (hb) for the gather and
// el/er via shfl reduce. No fp32 C store.
template<int NCOLS, int H>
__global__ __launch_bounds__(256) void gemm_eler(const float* __restrict__ A,
    const float* __restrict__ B, const float* __restrict__ al, const float* __restrict__ ar,
    unsigned short* __restrict__ hb, float* __restrict__ el, float* __restrict__ er, int M) {
  constexpr int K = 128;
  constexpr int TM = 64;
  constexpr int F = NCOLS / H;
  __shared__ float As[TM][K];              // 32 KB
  const int tid = threadIdx.x;
  const int m0 = blockIdx.x * TM;

  for (int i = tid; i < TM * K / 4; i += 256) {
    const int m = (i * 4) / K, k = (i * 4) % K;
    float4 v = make_float4(0.f, 0.f, 0.f, 0.f);
    if (m0 + m < M) v = *reinterpret_cast<const float4*>(&A[(size_t)(m0 + m) * K + k]);
    *reinterpret_cast<float4*>(&As[m][k]) = v;
  }
  __syncthreads();

  constexpr int CW = NCOLS / 32;           // cols per thread: 4 or 2
  const int c0 = (tid & 31) * CW;
  const int n0 = (tid >> 5) * 8;
  float acc[8][CW];
  #pragma unroll
  for (int i = 0; i < 8; ++i)
    #pragma unroll
    for (int j = 0; j < CW; ++j) acc[i][j] = 0.f;

  #pragma unroll 4
  for (int k = 0; k < K; ++k) {
    float wv[CW];
    if constexpr (CW == 4)
      *reinterpret_cast<float4*>(&wv[0]) = *reinterpret_cast<const float4*>(&B[(size_t)k * NCOLS + c0]);
    else
      *reinterpret_cast<float2*>(&wv[0]) = *reinterpret_cast<const float2*>(&B[(size_t)k * NCOLS + c0]);
    float xv[8];
    #pragma unroll
    for (int i = 0; i < 8; ++i) xv[i] = As[n0 + i][k];
    #pragma unroll
    for (int i = 0; i < 8; ++i)
      #pragma unroll
      for (int j = 0; j < CW; ++j)
        acc[i][j] = fmaf(xv[i], wv[j], acc[i][j]);
  }

  float alv[CW], arv[CW];
  if constexpr (CW == 4) {
    *reinterpret_cast<float4*>(&alv[0]) = *reinterpret_cast<const float4*>(&al[c0]);
    *reinterpret_cast<float4*>(&arv[0]) = *reinterpret_cast<const float4*>(&ar[c0]);
  } else {
    *reinterpret_cast<float2*>(&alv[0]) = *reinterpret_cast<const float2*>(&al[c0]);
    *reinterpret_cast<float2*>(&arv[0]) = *reinterpret_cast<const float2*>(&ar[c0]);
  }
  constexpr int GRP = F / CW;              // lanes per head group
  const int h = c0 / F;

  #pragma unroll
  for (int i = 0; i < 8; ++i) {
    const int m = m0 + n0 + i;
    if (m < M) {
      // bf16 feature row for the gather
      if constexpr (CW == 4) {
        ushort4 u;
        u.x = f2bf(acc[i][0]); u.y = f2bf(acc[i][1]);
        u.z = f2bf(acc[i][2]); u.w = f2bf(acc[i][3]);
        *reinterpret_cast<ushort4*>(&hb[(size_t)m * NCOLS + c0]) = u;
      } else {
        ushort2 u;
        u.x = f2bf(acc[i][0]); u.y = f2bf(acc[i][1]);
        *reinterpret_cast<ushort2*>(&hb[(size_t)m * NCOLS + c0]) = u;
      }
    }
    // fused el/er
    float pl = 0.f, pr = 0.f;
    #pragma unroll
    for (int j = 0; j < CW; ++j) {
      pl = fmaf(alv[j], acc[i][j], pl);
      pr = fmaf(arv[j], acc[i][j], pr);
    }
    #pragma unroll
    for (int off = 1; off < GRP; off <<= 1) {
      pl += __shfl_xor(pl, off);
      pr += __shfl_xor(pr, off);
    }
    if (((tid & 31) & (GRP - 1)) == 0 && m < M) {
      el[(size_t)m * H + h] = pl;
      er[(size_t)m * H + h] = pr;
    }
  }
}

// ---------------- CSR build ----------------
__global__ __launch_bounds__(256) void hist_kernel(const int* __restrict__ dst,
    int* deg, int E) {
  const int e = blockIdx.x * 256 + threadIdx.x;
  if (e < E) atomicAdd(&deg[dst[e]], 1);
}

__global__ __launch_bounds__(256) void block_sum_kernel(const int* __restrict__ deg,
    int* __restrict__ partials, int N) {
  __shared__ int wsum[4];
  const int tid = threadIdx.x;
  const int base = blockIdx.x * 1024 + tid * 4;
  int s = 0;
  #pragma unroll
  for (int j = 0; j < 4; ++j) if (base + j < N) s += deg[base + j];
  #pragma unroll
  for (int off = 32; off >= 1; off >>= 1) s += __shfl_down(s, off);
  if ((tid & 63) == 0) wsum[tid >> 6] = s;
  __syncthreads();
  if (tid == 0) partials[blockIdx.x] = wsum[0] + wsum[1] + wsum[2] + wsum[3];
}

__global__ __launch_bounds__(64) void scan_partials_kernel(int* partials, int nb) {
  const int tid = threadIdx.x;
  int v = (tid < nb) ? partials[tid] : 0;
  int incl = v;
  #pragma unroll
  for (int off = 1; off < 64; off <<= 1) {
    const int t = __shfl_up(incl, off);
    if (tid >= off) incl += t;
  }
  if (tid < nb) partials[tid] = incl - v;   // exclusive
}

__global__ __launch_bounds__(256) void block_scan_kernel(const int* __restrict__ deg,
    const int* __restrict__ partials, int* __restrict__ row_ptr,
    int* __restrict__ cursor, int N, int E) {
  __shared__ int wtot[4];
  const int tid = threadIdx.x;
  const int lane = tid & 63, wid = tid >> 6;
  const int idx = blockIdx.x * 1024 + tid * 4;
  int v[4];
  #pragma unroll
  for (int j = 0; j < 4; ++j) v[j] = (idx + j < N) ? deg[idx + j] : 0;
  const int tsum = v[0] + v[1] + v[2] + v[3];
  int incl = tsum;
  #pragma unroll
  for (int off = 1; off < 64; off <<= 1) {
    const int t = __shfl_up(incl, off);
    if (lane >= off) incl += t;
  }
  if (lane == 63) wtot[wid] = incl;
  __syncthreads();
  int excl = partials[blockIdx.x] + incl - tsum;
  for (int w = 0; w < wid; ++w) excl += wtot[w];
  #pragma unroll
  for (int j = 0; j < 4; ++j) {
    if (idx + j < N) { row_ptr[idx + j] = excl; cursor[idx + j] = excl; excl += v[j]; }
  }
  if (blockIdx.x == 0 && tid == 0) row_ptr[N] = E;
}

__global__ __launch_bounds__(256) void place_kernel(const int* __restrict__ src,
    const int* __restrict__ dst, int* cursor, int* __restrict__ csr_src, int E) {
  const int e = blockIdx.x * 256 + threadIdx.x;
  if (e < E) {
    const int pos = atomicAdd(&cursor[dst[e]], 1);
    csr_src[pos] = src[e];
  }
}

// ---------------- fused aggregate: one wave per dst node, bf16 gather ----------------
template<int H, int F>
__global__ __launch_bounds__(256) void gat_agg(const int* __restrict__ row_ptr,
    const int* __restrict__ csr_src, const float* __restrict__ el,
    const float* __restrict__ er, const unsigned short* __restrict__ hb,
    const float* __restrict__ bias, float* __restrict__ out, int N) {
  constexpr int HF = H * F;
  constexpr int CPL = HF / 64;             // 2 (layer1) or 1 (layer2)
  const int wid = threadIdx.x >> 6;
  const int d = blockIdx.x * 4 + wid;
  if (d >= N) return;
  const int lane = threadIdx.x & 63;
  const int c0 = lane * CPL;
  const int h = c0 / F;
  const float erd = er[(size_t)d * H + h];
  const int beg = row_ptr[d], end = row_ptr[d + 1];
  float a0 = 0.f, a1 = 0.f, denom = 0.f;
  int i = beg;

  // 8-edge batches: independent idx->el->hb chains in flight
  for (; i + 8 <= end; i += 8) {
    int s[8];
    #pragma unroll
    for (int j = 0; j < 8; ++j) s[j] = csr_src[i + j];
    float ee[8];
    #pragma unroll
    for (int j = 0; j < 8; ++j) ee[j] = el[(size_t)s[j] * H + h];
    if constexpr (CPL == 2) {
      ushort2 u[8];
      #pragma unroll
      for (int j = 0; j < 8; ++j)
        u[j] = *reinterpret_cast<const ushort2*>(&hb[(size_t)s[j] * HF + c0]);
      #pragma unroll
      for (int j = 0; j < 8; ++j) {
        float t = ee[j] + erd; t = t > 0.f ? t : NEG_SLOPE * t;
        const float x = __expf(t);
        denom += x;
        a0 = fmaf(x, bf2f(u[j].x), a0); a1 = fmaf(x, bf2f(u[j].y), a1);
      }
    } else {
      unsigned short u[8];
      #pragma unroll
      for (int j = 0; j < 8; ++j) u[j] = hb[(size_t)s[j] * HF + c0];
      #pragma unroll
      for (int j = 0; j < 8; ++j) {
        float t = ee[j] + erd; t = t > 0.f ? t : NEG_SLOPE * t;
        const float x = __expf(t);
        denom += x;
        a0 = fmaf(x, bf2f(u[j]), a0);
      }
    }
  }
  for (; i + 4 <= end; i += 4) {
    int s[4];
    #pragma unroll
    for (int j = 0; j < 4; ++j) s[j] = csr_src[i + j];
    float ee[4];
    #pragma unroll
    for (int j = 0; j < 4; ++j) ee[j] = el[(size_t)s[j] * H + h];
    if constexpr (CPL == 2) {
      ushort2 u[4];
      #pragma unroll
      for (int j = 0; j < 4; ++j)
        u[j] = *reinterpret_cast<const ushort2*>(&hb[(size_t)s[j] * HF + c0]);
      #pragma unroll
      for (int j = 0; j < 4; ++j) {
        float t = ee[j] + erd; t = t > 0.f ? t : NEG_SLOPE * t;
        const float x = __expf(t);
        denom += x;
        a0 = fmaf(x, bf2f(u[j].x), a0); a1 = fmaf(x, bf2f(u[j].y), a1);
      }
    } else {
      unsigned short u[4];
      #pragma unroll
      for (int j = 0; j < 4; ++j) u[j] = hb[(size_t)s[j] * HF + c0];
      #pragma unroll
      for (int j = 0; j < 4; ++j) {
        float t = ee[j] + erd; t = t > 0.f ? t : NEG_SLOPE * t;
        const float x = __expf(t);
        denom += x;
        a0 = fmaf(x, bf2f(u[j]), a0);
      }
    }
  }
  for (; i < end; ++i) {
    const int s = csr_src[i];
    float t = el[(size_t)s * H + h] + erd;
    t = t > 0.f ? t : NEG_SLOPE * t;
    const float x = __expf(t);
    denom += x;
    if constexpr (CPL == 2) {
      const ushort2 u = *reinterpret_cast<const ushort2*>(&hb[(size_t)s * HF + c0]);
      a0 = fmaf(x, bf2f(u.x), a0); a1 = fmaf(x, bf2f(u.y), a1);
    } else {
      a0 = fmaf(x, bf2f(hb[(size_t)s * HF + c0]), a0);
    }
  }

  const float inv = denom > 0.f ? 1.f / denom : 0.f;   // deg==0 -> out = bias
  if constexpr (CPL == 2) {
    float2 o;
    o.x = bias[c0] + a0 * inv;
    o.y = bias[c0 + 1] + a1 * inv;
    *reinterpret_cast<float2*>(&out[(size_t)d * HF + c0]) = o;
  } else {
    out[(size_t)d * HF + c0] = bias[c0] + a0 * inv;
  }
}

extern "C" void kernel_launch(void* const* d_in, const int* in_sizes, int n_in,
                              void* d_out, int out_size, void* d_ws, size_t ws_size,
                              hipStream_t stream) {
  const float* x   = (const float*)d_in[0];
  const float* W1  = (const float*)d_in[1];
  const float* al1 = (const float*)d_in[2];
  const float* ar1 = (const float*)d_in[3];
  const float* b1  = (const float*)d_in[4];
  const float* W2  = (const float*)d_in[5];
  const float* al2 = (const float*)d_in[6];
  const float* ar2 = (const float*)d_in[7];
  const float* b2  = (const float*)d_in[8];
  const int* src   = (const int*)d_in[9];
  const int* dst   = (const int*)d_in[10];
  const int N = in_sizes[0] / 128;
  const int E = in_sizes[9];
  float* out = (float*)d_out;

  // workspace layout
  float* ws   = (float*)d_ws;
  float* out1 = ws;                          // N*128 f32 (layer-1 output, layer-2 input)
  float* el1  = out1 + (size_t)N * 128;      // N*4
  float* er1  = el1 + (size_t)N * 4;         // N*4
  float* el2  = er1 + (size_t)N * 4;         // N
  float* er2  = el2 + N;                     // N
  int* deg     = (int*)(er2 + N);            // N
  int* row_ptr = deg + N;                    // N+1
  int* cursor  = row_ptr + N + 1;            // N
  int* csr_src = cursor + N;                 // E
  int* partials = csr_src + E;               // ~N/1024+1
  unsigned short* hb1 = (unsigned short*)(partials + 64);  // N*128 bf16
  unsigned short* hb2 = hb1 + (size_t)N * 128;             // N*64 bf16

  const dim3 blk(256);
  const int nb = (N + 1023) / 1024;

  // ---- CSR build (shared by both layers) ----
  hipMemsetAsync(deg, 0, (size_t)N * sizeof(int), stream);
  hist_kernel<<<dim3((E + 255) / 256), blk, 0, stream>>>(dst, deg, E);
  block_sum_kernel<<<dim3(nb), blk, 0, stream>>>(deg, partials, N);
  scan_partials_kernel<<<dim3(1), dim3(64), 0, stream>>>(partials, nb);
  block_scan_kernel<<<dim3(nb), blk, 0, stream>>>(deg, partials, row_ptr, cursor, N, E);
  place_kernel<<<dim3((E + 255) / 256), blk, 0, stream>>>(src, dst, cursor, csr_src, E);

  // ---- layer 1: 128 -> H=4, F=32 ----
  gemm_eler<128, 4><<<dim3((N + 63) / 64), blk, 0, stream>>>(x, W1, al1, ar1, hb1, el1, er1, N);
  gat_agg<4, 32><<<dim3((N + 3) / 4), blk, 0, stream>>>(row_ptr, csr_src, el1, er1, hb1, b1, out1, N);

  // ---- layer 2: 128 -> H=1, F=64 ----
  gemm_eler<64, 1><<<dim3((N + 63) / 64), blk, 0, stream>>>(out1, W2, al2, ar2, hb2, el2, er2, N);
  gat_agg<1, 64><<<dim3((N + 3) / 4), blk, 0, stream>>>(row_ptr, csr_src, el2, er2, hb2, b2, out, N);
}

// Round 10
// 197.689 us; speedup vs baseline: 4.3312x; 1.1982x over previous
//
#include <hip/hip_runtime.h>

#define NEG_SLOPE 0.2f

// float -> bf16 bits, round-to-nearest-even (finite inputs)
static __device__ __forceinline__ unsigned short f2bf(float f) {
  unsigned x = __float_as_uint(f);
  return (unsigned short)((x + 0x7FFFu + ((x >> 16) & 1u)) >> 16);
}
static __device__ __forceinline__ float bf2f(unsigned short u) {
  return __uint_as_float((unsigned)u << 16);
}

// ------------- GEMM + fused el/er + bf16 feature emit -------------
template<int NCOLS, int H>
__global__ __launch_bounds__(256) void gemm_eler(const float* __restrict__ A,
    const float* __restrict__ B, const float* __restrict__ al, const float* __restrict__ ar,
    unsigned short* __restrict__ hb, float* __restrict__ el, float* __restrict__ er, int M) {
  constexpr int K = 128;
  constexpr int TM = 64;
  constexpr int F = NCOLS / H;
  __shared__ float As[TM][K];              // 32 KB
  const int tid = threadIdx.x;
  const int m0 = blockIdx.x * TM;

  for (int i = tid; i < TM * K / 4; i += 256) {
    const int m = (i * 4) / K, k = (i * 4) % K;
    float4 v = make_float4(0.f, 0.f, 0.f, 0.f);
    if (m0 + m < M) v = *reinterpret_cast<const float4*>(&A[(size_t)(m0 + m) * K + k]);
    *reinterpret_cast<float4*>(&As[m][k]) = v;
  }
  __syncthreads();

  constexpr int CW = NCOLS / 32;           // cols per thread: 4 or 2
  const int c0 = (tid & 31) * CW;
  const int n0 = (tid >> 5) * 8;
  float acc[8][CW];
  #pragma unroll
  for (int i = 0; i < 8; ++i)
    #pragma unroll
    for (int j = 0; j < CW; ++j) acc[i][j] = 0.f;

  #pragma unroll 4
  for (int k = 0; k < K; ++k) {
    float wv[CW];
    if constexpr (CW == 4)
      *reinterpret_cast<float4*>(&wv[0]) = *reinterpret_cast<const float4*>(&B[(size_t)k * NCOLS + c0]);
    else
      *reinterpret_cast<float2*>(&wv[0]) = *reinterpret_cast<const float2*>(&B[(size_t)k * NCOLS + c0]);
    float xv[8];
    #pragma unroll
    for (int i = 0; i < 8; ++i) xv[i] = As[n0 + i][k];
    #pragma unroll
    for (int i = 0; i < 8; ++i)
      #pragma unroll
      for (int j = 0; j < CW; ++j)
        acc[i][j] = fmaf(xv[i], wv[j], acc[i][j]);
  }

  float alv[CW], arv[CW];
  if constexpr (CW == 4) {
    *reinterpret_cast<float4*>(&alv[0]) = *reinterpret_cast<const float4*>(&al[c0]);
    *reinterpret_cast<float4*>(&arv[0]) = *reinterpret_cast<const float4*>(&ar[c0]);
  } else {
    *reinterpret_cast<float2*>(&alv[0]) = *reinterpret_cast<const float2*>(&al[c0]);
    *reinterpret_cast<float2*>(&arv[0]) = *reinterpret_cast<const float2*>(&ar[c0]);
  }
  constexpr int GRP = F / CW;              // lanes per head group
  const int h = c0 / F;

  #pragma unroll
  for (int i = 0; i < 8; ++i) {
    const int m = m0 + n0 + i;
    if (m < M) {
      if constexpr (CW == 4) {
        ushort4 u;
        u.x = f2bf(acc[i][0]); u.y = f2bf(acc[i][1]);
        u.z = f2bf(acc[i][2]); u.w = f2bf(acc[i][3]);
        *reinterpret_cast<ushort4*>(&hb[(size_t)m * NCOLS + c0]) = u;
      } else {
        ushort2 u;
        u.x = f2bf(acc[i][0]); u.y = f2bf(acc[i][1]);
        *reinterpret_cast<ushort2*>(&hb[(size_t)m * NCOLS + c0]) = u;
      }
    }
    float pl = 0.f, pr = 0.f;
    #pragma unroll
    for (int j = 0; j < CW; ++j) {
      pl = fmaf(alv[j], acc[i][j], pl);
      pr = fmaf(arv[j], acc[i][j], pr);
    }
    #pragma unroll
    for (int off = 1; off < GRP; off <<= 1) {
      pl += __shfl_xor(pl, off);
      pr += __shfl_xor(pr, off);
    }
    if (((tid & 31) & (GRP - 1)) == 0 && m < M) {
      el[(size_t)m * H + h] = pl;
      er[(size_t)m * H + h] = pr;
    }
  }
}

// ---------------- CSR build ----------------
// rank pass: rank[e] = slot of edge e within its dst bucket; deg ends as histogram
__global__ __launch_bounds__(256) void rank_kernel(const int* __restrict__ dst,
    int* deg, int* __restrict__ rank, int E) {
  const int e = blockIdx.x * 256 + threadIdx.x;
  if (e < E) rank[e] = atomicAdd(&deg[dst[e]], 1);
}

__global__ __launch_bounds__(256) void block_sum_kernel(const int* __restrict__ deg,
    int* __restrict__ partials, int N) {
  __shared__ int wsum[4];
  const int tid = threadIdx.x;
  const int base = blockIdx.x * 1024 + tid * 4;
  int s = 0;
  #pragma unroll
  for (int j = 0; j < 4; ++j) if (base + j < N) s += deg[base + j];
  #pragma unroll
  for (int off = 32; off >= 1; off >>= 1) s += __shfl_down(s, off);
  if ((tid & 63) == 0) wsum[tid >> 6] = s;
  __syncthreads();
  if (tid == 0) partials[blockIdx.x] = wsum[0] + wsum[1] + wsum[2] + wsum[3];
}

__global__ __launch_bounds__(64) void scan_partials_kernel(int* partials, int nb) {
  const int tid = threadIdx.x;
  int v = (tid < nb) ? partials[tid] : 0;
  int incl = v;
  #pragma unroll
  for (int off = 1; off < 64; off <<= 1) {
    const int t = __shfl_up(incl, off);
    if (tid >= off) incl += t;
  }
  if (tid < nb) partials[tid] = incl - v;   // exclusive
}

__global__ __launch_bounds__(256) void block_scan_kernel(const int* __restrict__ deg,
    const int* __restrict__ partials, int* __restrict__ row_ptr, int N, int E) {
  __shared__ int wtot[4];
  const int tid = threadIdx.x;
  const int lane = tid & 63, wid = tid >> 6;
  const int idx = blockIdx.x * 1024 + tid * 4;
  int v[4];
  #pragma unroll
  for (int j = 0; j < 4; ++j) v[j] = (idx + j < N) ? deg[idx + j] : 0;
  const int tsum = v[0] + v[1] + v[2] + v[3];
  int incl = tsum;
  #pragma unroll
  for (int off = 1; off < 64; off <<= 1) {
    const int t = __shfl_up(incl, off);
    if (lane >= off) incl += t;
  }
  if (lane == 63) wtot[wid] = incl;
  __syncthreads();
  int excl = partials[blockIdx.x] + incl - tsum;
  for (int w = 0; w < wid; ++w) excl += wtot[w];
  #pragma unroll
  for (int j = 0; j < 4; ++j) {
    if (idx + j < N) { row_ptr[idx + j] = excl; excl += v[j]; }
  }
  if (blockIdx.x == 0 && tid == 0) row_ptr[N] = E;
}

// atomic-free placement: pos = row_ptr[dst] + rank, fire-and-forget scatter
__global__ __launch_bounds__(256) void place_kernel(const int* __restrict__ src,
    const int* __restrict__ dst, const int* __restrict__ row_ptr,
    const int* __restrict__ rank, int* __restrict__ csr_src, int E) {
  const int e = blockIdx.x * 256 + threadIdx.x;
  if (e < E) {
    csr_src[row_ptr[dst[e]] + rank[e]] = src[e];
  }
}

// ---------------- fused aggregate: one wave per dst node, bf16 gather ----------------
template<int H, int F>
__global__ __launch_bounds__(256) void gat_agg(const int* __restrict__ row_ptr,
    const int* __restrict__ csr_src, const float* __restrict__ el,
    const float* __restrict__ er, const unsigned short* __restrict__ hb,
    const float* __restrict__ bias, float* __restrict__ out, int N) {
  constexpr int HF = H * F;
  constexpr int CPL = HF / 64;             // 2 (layer1) or 1 (layer2)
  const int wid = threadIdx.x >> 6;
  const int d = blockIdx.x * 4 + wid;
  if (d >= N) return;
  const int lane = threadIdx.x & 63;
  const int c0 = lane * CPL;
  const int h = c0 / F;
  const float erd = er[(size_t)d * H + h];
  const int beg = row_ptr[d], end = row_ptr[d + 1];
  float a0 = 0.f, a1 = 0.f, denom = 0.f;
  int i = beg;

  for (; i + 8 <= end; i += 8) {
    int s[8];
    #pragma unroll
    for (int j = 0; j < 8; ++j) s[j] = csr_src[i + j];
    float ee[8];
    #pragma unroll
    for (int j = 0; j < 8; ++j) ee[j] = el[(size_t)s[j] * H + h];
    if constexpr (CPL == 2) {
      ushort2 u[8];
      #pragma unroll
      for (int j = 0; j < 8; ++j)
        u[j] = *reinterpret_cast<const ushort2*>(&hb[(size_t)s[j] * HF + c0]);
      #pragma unroll
      for (int j = 0; j < 8; ++j) {
        float t = ee[j] + erd; t = t > 0.f ? t : NEG_SLOPE * t;
        const float x = __expf(t);
        denom += x;
        a0 = fmaf(x, bf2f(u[j].x), a0); a1 = fmaf(x, bf2f(u[j].y), a1);
      }
    } else {
      unsigned short u[8];
      #pragma unroll
      for (int j = 0; j < 8; ++j) u[j] = hb[(size_t)s[j] * HF + c0];
      #pragma unroll
      for (int j = 0; j < 8; ++j) {
        float t = ee[j] + erd; t = t > 0.f ? t : NEG_SLOPE * t;
        const float x = __expf(t);
        denom += x;
        a0 = fmaf(x, bf2f(u[j]), a0);
      }
    }
  }
  for (; i + 4 <= end; i += 4) {
    int s[4];
    #pragma unroll
    for (int j = 0; j < 4; ++j) s[j] = csr_src[i + j];
    float ee[4];
    #pragma unroll
    for (int j = 0; j < 4; ++j) ee[j] = el[(size_t)s[j] * H + h];
    if constexpr (CPL == 2) {
      ushort2 u[4];
      #pragma unroll
      for (int j = 0; j < 4; ++j)
        u[j] = *reinterpret_cast<const ushort2*>(&hb[(size_t)s[j] * HF + c0]);
      #pragma unroll
      for (int j = 0; j < 4; ++j) {
        float t = ee[j] + erd; t = t > 0.f ? t : NEG_SLOPE * t;
        const float x = __expf(t);
        denom += x;
        a0 = fmaf(x, bf2f(u[j].x), a0); a1 = fmaf(x, bf2f(u[j].y), a1);
      }
    } else {
      unsigned short u[4];
      #pragma unroll
      for (int j = 0; j < 4; ++j) u[j] = hb[(size_t)s[j] * HF + c0];
      #pragma unroll
      for (int j = 0; j < 4; ++j) {
        float t = ee[j] + erd; t = t > 0.f ? t : NEG_SLOPE * t;
        const float x = __expf(t);
        denom += x;
        a0 = fmaf(x, bf2f(u[j]), a0);
      }
    }
  }
  for (; i < end; ++i) {
    const int s = csr_src[i];
    float t = el[(size_t)s * H + h] + erd;
    t = t > 0.f ? t : NEG_SLOPE * t;
    const float x = __expf(t);
    denom += x;
    if constexpr (CPL == 2) {
      const ushort2 u = *reinterpret_cast<const ushort2*>(&hb[(size_t)s * HF + c0]);
      a0 = fmaf(x, bf2f(u.x), a0); a1 = fmaf(x, bf2f(u.y), a1);
    } else {
      a0 = fmaf(x, bf2f(hb[(size_t)s * HF + c0]), a0);
    }
  }

  const float inv = denom > 0.f ? 1.f / denom : 0.f;   // deg==0 -> out = bias
  if constexpr (CPL == 2) {
    float2 o;
    o.x = bias[c0] + a0 * inv;
    o.y = bias[c0 + 1] + a1 * inv;
    *reinterpret_cast<float2*>(&out[(size_t)d * HF + c0]) = o;
  } else {
    out[(size_t)d * HF + c0] = bias[c0] + a0 * inv;
  }
}

extern "C" void kernel_launch(void* const* d_in, const int* in_sizes, int n_in,
                              void* d_out, int out_size, void* d_ws, size_t ws_size,
                              hipStream_t stream) {
  const float* x   = (const float*)d_in[0];
  const float* W1  = (const float*)d_in[1];
  const float* al1 = (const float*)d_in[2];
  const float* ar1 = (const float*)d_in[3];
  const float* b1  = (const float*)d_in[4];
  const float* W2  = (const float*)d_in[5];
  const float* al2 = (const float*)d_in[6];
  const float* ar2 = (const float*)d_in[7];
  const float* b2  = (const float*)d_in[8];
  const int* src   = (const int*)d_in[9];
  const int* dst   = (const int*)d_in[10];
  const int N = in_sizes[0] / 128;
  const int E = in_sizes[9];
  float* out = (float*)d_out;

  // workspace layout
  float* ws   = (float*)d_ws;
  float* out1 = ws;                          // N*128 f32 (layer-1 output, layer-2 input)
  float* el1  = out1 + (size_t)N * 128;      // N*4
  float* er1  = el1 + (size_t)N * 4;         // N*4
  float* el2  = er1 + (size_t)N * 4;         // N
  float* er2  = el2 + N;                     // N
  int* deg     = (int*)(er2 + N);            // N
  int* row_ptr = deg + N;                    // N+1
  int* rank    = row_ptr + N + 1;            // E
  int* csr_src = rank + E;                   // E
  int* partials = csr_src + E;               // ~N/1024+1
  unsigned short* hb1 = (unsigned short*)(partials + 64);  // N*128 bf16
  unsigned short* hb2 = hb1 + (size_t)N * 128;             // N*64 bf16

  const dim3 blk(256);
  const int nb = (N + 1023) / 1024;

  // ---- CSR build (shared by both layers) ----
  hipMemsetAsync(deg, 0, (size_t)N * sizeof(int), stream);
  rank_kernel<<<dim3((E + 255) / 256), blk, 0, stream>>>(dst, deg, rank, E);
  block_sum_kernel<<<dim3(nb), blk, 0, stream>>>(deg, partials, N);
  scan_partials_kernel<<<dim3(1), dim3(64), 0, stream>>>(partials, nb);
  block_scan_kernel<<<dim3(nb), blk, 0, stream>>>(deg, partials, row_ptr, N, E);
  place_kernel<<<dim3((E + 255) / 256), blk, 0, stream>>>(src, dst, row_ptr, rank, csr_src, E);

  // ---- layer 1: 128 -> H=4, F=32 ----
  gemm_eler<128, 4><<<dim3((N + 63) / 64), blk, 0, stream>>>(x, W1, al1, ar1, hb1, el1, er1, N);
  gat_agg<4, 32><<<dim3((N + 3) / 4), blk, 0, stream>>>(row_ptr, csr_src, el1, er1, hb1, b1, out1, N);

  // ---- layer 2: 128 -> H=1, F=64 ----
  gemm_eler<64, 1><<<dim3((N + 63) / 64), blk, 0, stream>>>(out1, W2, al2, ar2, hb2, el2, er2, N);
  gat_agg<1, 64><<<dim3((N + 3) / 4), blk, 0, stream>>>(row_ptr, csr_src, el2, er2, hb2, b2, out, N);
}

// Round 11
// 186.093 us; speedup vs baseline: 4.6011x; 1.0623x over previous
//
#include <hip/hip_runtime.h>

#define NEG_SLOPE 0.2f

// float -> bf16 bits, round-to-nearest-even (finite inputs)
static __device__ __forceinline__ unsigned short f2bf(float f) {
  unsigned x = __float_as_uint(f);
  return (unsigned short)((x + 0x7FFFu + ((x >> 16) & 1u)) >> 16);
}
static __device__ __forceinline__ float bf2f(unsigned short u) {
  return __uint_as_float((unsigned)u << 16);
}

// ------------- GEMM + fused el/er + bf16 feature emit -------------
template<int NCOLS, int H>
__global__ __launch_bounds__(256) void gemm_eler(const float* __restrict__ A,
    const float* __restrict__ B, const float* __restrict__ al, const float* __restrict__ ar,
    unsigned short* __restrict__ hb, float* __restrict__ el, float* __restrict__ er, int M) {
  constexpr int K = 128;
  constexpr int TM = 64;
  constexpr int F = NCOLS / H;
  __shared__ float As[TM][K];              // 32 KB
  const int tid = threadIdx.x;
  const int m0 = blockIdx.x * TM;

  for (int i = tid; i < TM * K / 4; i += 256) {
    const int m = (i * 4) / K, k = (i * 4) % K;
    float4 v = make_float4(0.f, 0.f, 0.f, 0.f);
    if (m0 + m < M) v = *reinterpret_cast<const float4*>(&A[(size_t)(m0 + m) * K + k]);
    *reinterpret_cast<float4*>(&As[m][k]) = v;
  }
  __syncthreads();

  constexpr int CW = NCOLS / 32;           // cols per thread: 4 or 2
  const int c0 = (tid & 31) * CW;
  const int n0 = (tid >> 5) * 8;
  float acc[8][CW];
  #pragma unroll
  for (int i = 0; i < 8; ++i)
    #pragma unroll
    for (int j = 0; j < CW; ++j) acc[i][j] = 0.f;

  #pragma unroll 4
  for (int k = 0; k < K; ++k) {
    float wv[CW];
    if constexpr (CW == 4)
      *reinterpret_cast<float4*>(&wv[0]) = *reinterpret_cast<const float4*>(&B[(size_t)k * NCOLS + c0]);
    else
      *reinterpret_cast<float2*>(&wv[0]) = *reinterpret_cast<const float2*>(&B[(size_t)k * NCOLS + c0]);
    float xv[8];
    #pragma unroll
    for (int i = 0; i < 8; ++i) xv[i] = As[n0 + i][k];
    #pragma unroll
    for (int i = 0; i < 8; ++i)
      #pragma unroll
      for (int j = 0; j < CW; ++j)
        acc[i][j] = fmaf(xv[i], wv[j], acc[i][j]);
  }

  float alv[CW], arv[CW];
  if constexpr (CW == 4) {
    *reinterpret_cast<float4*>(&alv[0]) = *reinterpret_cast<const float4*>(&al[c0]);
    *reinterpret_cast<float4*>(&arv[0]) = *reinterpret_cast<const float4*>(&ar[c0]);
  } else {
    *reinterpret_cast<float2*>(&alv[0]) = *reinterpret_cast<const float2*>(&al[c0]);
    *reinterpret_cast<float2*>(&arv[0]) = *reinterpret_cast<const float2*>(&ar[c0]);
  }
  constexpr int GRP = F / CW;              // lanes per head group
  const int h = c0 / F;

  #pragma unroll
  for (int i = 0; i < 8; ++i) {
    const int m = m0 + n0 + i;
    if (m < M) {
      if constexpr (CW == 4) {
        ushort4 u;
        u.x = f2bf(acc[i][0]); u.y = f2bf(acc[i][1]);
        u.z = f2bf(acc[i][2]); u.w = f2bf(acc[i][3]);
        *reinterpret_cast<ushort4*>(&hb[(size_t)m * NCOLS + c0]) = u;
      } else {
        ushort2 u;
        u.x = f2bf(acc[i][0]); u.y = f2bf(acc[i][1]);
        *reinterpret_cast<ushort2*>(&hb[(size_t)m * NCOLS + c0]) = u;
      }
    }
    float pl = 0.f, pr = 0.f;
    #pragma unroll
    for (int j = 0; j < CW; ++j) {
      pl = fmaf(alv[j], acc[i][j], pl);
      pr = fmaf(arv[j], acc[i][j], pr);
    }
    #pragma unroll
    for (int off = 1; off < GRP; off <<= 1) {
      pl += __shfl_xor(pl, off);
      pr += __shfl_xor(pr, off);
    }
    if (((tid & 31) & (GRP - 1)) == 0 && m < M) {
      el[(size_t)m * H + h] = pl;
      er[(size_t)m * H + h] = pr;
    }
  }
}

// ---------------- CSR build ----------------
__global__ __launch_bounds__(256) void rank_kernel(const int* __restrict__ dst,
    int* deg, int* __restrict__ rank, int E) {
  const int e = blockIdx.x * 256 + threadIdx.x;
  if (e < E) rank[e] = atomicAdd(&deg[dst[e]], 1);
}

__global__ __launch_bounds__(256) void block_sum_kernel(const int* __restrict__ deg,
    int* __restrict__ partials, int N) {
  __shared__ int wsum[4];
  const int tid = threadIdx.x;
  const int base = blockIdx.x * 1024 + tid * 4;
  int s = 0;
  #pragma unroll
  for (int j = 0; j < 4; ++j) if (base + j < N) s += deg[base + j];
  #pragma unroll
  for (int off = 32; off >= 1; off >>= 1) s += __shfl_down(s, off);
  if ((tid & 63) == 0) wsum[tid >> 6] = s;
  __syncthreads();
  if (tid == 0) partials[blockIdx.x] = wsum[0] + wsum[1] + wsum[2] + wsum[3];
}

__global__ __launch_bounds__(64) void scan_partials_kernel(int* partials, int nb) {
  const int tid = threadIdx.x;
  int v = (tid < nb) ? partials[tid] : 0;
  int incl = v;
  #pragma unroll
  for (int off = 1; off < 64; off <<= 1) {
    const int t = __shfl_up(incl, off);
    if (tid >= off) incl += t;
  }
  if (tid < nb) partials[tid] = incl - v;   // exclusive
}

__global__ __launch_bounds__(256) void block_scan_kernel(const int* __restrict__ deg,
    const int* __restrict__ partials, int* __restrict__ row_ptr, int N, int E) {
  __shared__ int wtot[4];
  const int tid = threadIdx.x;
  const int lane = tid & 63, wid = tid >> 6;
  const int idx = blockIdx.x * 1024 + tid * 4;
  int v[4];
  #pragma unroll
  for (int j = 0; j < 4; ++j) v[j] = (idx + j < N) ? deg[idx + j] : 0;
  const int tsum = v[0] + v[1] + v[2] + v[3];
  int incl = tsum;
  #pragma unroll
  for (int off = 1; off < 64; off <<= 1) {
    const int t = __shfl_up(incl, off);
    if (lane >= off) incl += t;
  }
  if (lane == 63) wtot[wid] = incl;
  __syncthreads();
  int excl = partials[blockIdx.x] + incl - tsum;
  for (int w = 0; w < wid; ++w) excl += wtot[w];
  #pragma unroll
  for (int j = 0; j < 4; ++j) {
    if (idx + j < N) { row_ptr[idx + j] = excl; excl += v[j]; }
  }
  if (blockIdx.x == 0 && tid == 0) row_ptr[N] = E;
}

// atomic-free placement; csr entries are ushort (src ids < 65536)
__global__ __launch_bounds__(256) void place_kernel(const int* __restrict__ src,
    const int* __restrict__ dst, const int* __restrict__ row_ptr,
    const int* __restrict__ rank, unsigned short* __restrict__ csr_src, int E) {
  const int e = blockIdx.x * 256 + threadIdx.x;
  if (e < E) {
    csr_src[row_ptr[dst[e]] + rank[e]] = (unsigned short)src[e];
  }
}

// ------- fused aggregate: NPW dst nodes per wave, CPL=4, bf16 gather -------
// LPN = 64/NPW lanes per node; each lane owns 4 consecutive cols (ushort4).
template<int H, int F, int NPW>
__global__ __launch_bounds__(256) void gat_agg(const int* __restrict__ row_ptr,
    const unsigned short* __restrict__ csr_src, const float* __restrict__ el,
    const float* __restrict__ er, const unsigned short* __restrict__ hb,
    const float* __restrict__ bias, float* __restrict__ out, int N) {
  constexpr int HF = H * F;
  constexpr int LPN = 64 / NPW;            // lanes per node: 32 (L1) / 16 (L2)
  constexpr int CPL = HF / LPN;            // 4 in both layers
  static_assert(CPL == 4, "CPL must be 4");
  const int wid = threadIdx.x >> 6;
  const int lane = threadIdx.x & 63;
  const int g = lane / LPN;                // node slot within wave
  const int gl = lane % LPN;               // lane within node group
  const int d = (blockIdx.x * 4 + wid) * NPW + g;
  if (d >= N) return;
  const int c0 = gl * CPL;
  const int h = c0 / F;
  const float erd = er[(size_t)d * H + h];
  const int beg = row_ptr[d], end = row_ptr[d + 1];
  float a0 = 0.f, a1 = 0.f, a2 = 0.f, a3 = 0.f, denom = 0.f;
  int i = beg;

  for (; i + 8 <= end; i += 8) {
    int s[8];
    #pragma unroll
    for (int j = 0; j < 8; ++j) s[j] = csr_src[i + j];
    float ee[8];
    #pragma unroll
    for (int j = 0; j < 8; ++j) ee[j] = el[(size_t)s[j] * H + h];
    ushort4 u[8];
    #pragma unroll
    for (int j = 0; j < 8; ++j)
      u[j] = *reinterpret_cast<const ushort4*>(&hb[(size_t)s[j] * HF + c0]);
    #pragma unroll
    for (int j = 0; j < 8; ++j) {
      float t = ee[j] + erd;
      t = fmaxf(t, NEG_SLOPE * t);
      const float x = __expf(t);
      denom += x;
      a0 = fmaf(x, bf2f(u[j].x), a0); a1 = fmaf(x, bf2f(u[j].y), a1);
      a2 = fmaf(x, bf2f(u[j].z), a2); a3 = fmaf(x, bf2f(u[j].w), a3);
    }
  }
  for (; i + 4 <= end; i += 4) {
    int s[4];
    #pragma unroll
    for (int j = 0; j < 4; ++j) s[j] = csr_src[i + j];
    float ee[4];
    #pragma unroll
    for (int j = 0; j < 4; ++j) ee[j] = el[(size_t)s[j] * H + h];
    ushort4 u[4];
    #pragma unroll
    for (int j = 0; j < 4; ++j)
      u[j] = *reinterpret_cast<const ushort4*>(&hb[(size_t)s[j] * HF + c0]);
    #pragma unroll
    for (int j = 0; j < 4; ++j) {
      float t = ee[j] + erd;
      t = fmaxf(t, NEG_SLOPE * t);
      const float x = __expf(t);
      denom += x;
      a0 = fmaf(x, bf2f(u[j].x), a0); a1 = fmaf(x, bf2f(u[j].y), a1);
      a2 = fmaf(x, bf2f(u[j].z), a2); a3 = fmaf(x, bf2f(u[j].w), a3);
    }
  }
  for (; i < end; ++i) {
    const int s = csr_src[i];
    float t = el[(size_t)s * H + h] + erd;
    t = fmaxf(t, NEG_SLOPE * t);
    const float x = __expf(t);
    denom += x;
    const ushort4 u = *reinterpret_cast<const ushort4*>(&hb[(size_t)s * HF + c0]);
    a0 = fmaf(x, bf2f(u.x), a0); a1 = fmaf(x, bf2f(u.y), a1);
    a2 = fmaf(x, bf2f(u.z), a2); a3 = fmaf(x, bf2f(u.w), a3);
  }

  const float inv = denom > 0.f ? 1.f / denom : 0.f;   // deg==0 -> out = bias
  const float4 bv = *reinterpret_cast<const float4*>(&bias[c0]);
  float4 o;
  o.x = bv.x + a0 * inv; o.y = bv.y + a1 * inv;
  o.z = bv.z + a2 * inv; o.w = bv.w + a3 * inv;
  *reinterpret_cast<float4*>(&out[(size_t)d * HF + c0]) = o;
}

extern "C" void kernel_launch(void* const* d_in, const int* in_sizes, int n_in,
                              void* d_out, int out_size, void* d_ws, size_t ws_size,
                              hipStream_t stream) {
  const float* x   = (const float*)d_in[0];
  const float* W1  = (const float*)d_in[1];
  const float* al1 = (const float*)d_in[2];
  const float* ar1 = (const float*)d_in[3];
  const float* b1  = (const float*)d_in[4];
  const float* W2  = (const float*)d_in[5];
  const float* al2 = (const float*)d_in[6];
  const float* ar2 = (const float*)d_in[7];
  const float* b2  = (const float*)d_in[8];
  const int* src   = (const int*)d_in[9];
  const int* dst   = (const int*)d_in[10];
  const int N = in_sizes[0] / 128;
  const int E = in_sizes[9];
  float* out = (float*)d_out;

  // workspace layout
  float* ws   = (float*)d_ws;
  float* out1 = ws;                          // N*128 f32 (layer-1 output, layer-2 input)
  float* el1  = out1 + (size_t)N * 128;      // N*4
  float* er1  = el1 + (size_t)N * 4;         // N*4
  float* el2  = er1 + (size_t)N * 4;         // N
  float* er2  = el2 + N;                     // N
  int* deg     = (int*)(er2 + N);            // N
  int* row_ptr = deg + N;                    // N+1
  int* rank    = row_ptr + N + 1;            // E
  unsigned short* csr_src = (unsigned short*)(rank + E);   // E (ushort)
  int* partials = (int*)(csr_src + ((E + 1) & ~1));        // ~N/1024+1
  unsigned short* hb1 = (unsigned short*)(partials + 64);  // N*128 bf16
  unsigned short* hb2 = hb1 + (size_t)N * 128;             // N*64 bf16

  const dim3 blk(256);
  const int nb = (N + 1023) / 1024;

  // ---- CSR build (shared by both layers) ----
  hipMemsetAsync(deg, 0, (size_t)N * sizeof(int), stream);
  rank_kernel<<<dim3((E + 255) / 256), blk, 0, stream>>>(dst, deg, rank, E);
  block_sum_kernel<<<dim3(nb), blk, 0, stream>>>(deg, partials, N);
  scan_partials_kernel<<<dim3(1), dim3(64), 0, stream>>>(partials, nb);
  block_scan_kernel<<<dim3(nb), blk, 0, stream>>>(deg, partials, row_ptr, N, E);
  place_kernel<<<dim3((E + 255) / 256), blk, 0, stream>>>(src, dst, row_ptr, rank, csr_src, E);

  // ---- layer 1: 128 -> H=4, F=32; 2 nodes/wave ----
  gemm_eler<128, 4><<<dim3((N + 63) / 64), blk, 0, stream>>>(x, W1, al1, ar1, hb1, el1, er1, N);
  gat_agg<4, 32, 2><<<dim3((N + 7) / 8), blk, 0, stream>>>(row_ptr, csr_src, el1, er1, hb1, b1, out1, N);

  // ---- layer 2: 128 -> H=1, F=64; 4 nodes/wave ----
  gemm_eler<64, 1><<<dim3((N + 63) / 64), blk, 0, stream>>>(out1, W2, al2, ar2, hb2, el2, er2, N);
  gat_agg<1, 64, 4><<<dim3((N + 15) / 16), blk, 0, stream>>>(row_ptr, csr_src, el2, er2, hb2, b2, out, N);
}

// Round 12
// 168.592 us; speedup vs baseline: 5.0787x; 1.1038x over previous
//
#include <hip/hip_runtime.h>

#define NEG_SLOPE 0.2f

// float -> bf16 bits, round-to-nearest-even (finite inputs)
static __device__ __forceinline__ unsigned short f2bf(float f) {
  unsigned x = __float_as_uint(f);
  return (unsigned short)((x + 0x7FFFu + ((x >> 16) & 1u)) >> 16);
}
static __device__ __forceinline__ float bf2f(unsigned short u) {
  return __uint_as_float((unsigned)u << 16);
}

// ------- GEMM + fused el/er + bf16 emit, with optional rank blocks packed in -------
// Blocks [0, gemmBlocks) do the GEMM; blocks [gemmBlocks, ...) do the CSR rank pass
// (independent work packed into the same dispatch to overlap the serial CSR chain).
template<int NCOLS, int H>
__global__ __launch_bounds__(256) void gemm_eler_rank(const float* __restrict__ A,
    const float* __restrict__ B, const float* __restrict__ al, const float* __restrict__ ar,
    unsigned short* __restrict__ hb, float* __restrict__ el, float* __restrict__ er, int M,
    int gemmBlocks, const int* __restrict__ dst, int* deg, int* __restrict__ rank, int E) {
  constexpr int K = 128;
  constexpr int TM = 64;
  constexpr int F = NCOLS / H;
  __shared__ float As[TM][K];              // 32 KB
  const int tid = threadIdx.x;

  if (blockIdx.x >= gemmBlocks) {          // ---- rank blocks ----
    const int e = (blockIdx.x - gemmBlocks) * 256 + tid;
    if (e < E) rank[e] = atomicAdd(&deg[dst[e]], 1);
    return;
  }

  const int m0 = blockIdx.x * TM;
  for (int i = tid; i < TM * K / 4; i += 256) {
    const int m = (i * 4) / K, k = (i * 4) % K;
    float4 v = make_float4(0.f, 0.f, 0.f, 0.f);
    if (m0 + m < M) v = *reinterpret_cast<const float4*>(&A[(size_t)(m0 + m) * K + k]);
    *reinterpret_cast<float4*>(&As[m][k]) = v;
  }
  __syncthreads();

  constexpr int CW = NCOLS / 32;           // cols per thread: 4 or 2
  const int c0 = (tid & 31) * CW;
  const int n0 = (tid >> 5) * 8;
  float acc[8][CW];
  #pragma unroll
  for (int i = 0; i < 8; ++i)
    #pragma unroll
    for (int j = 0; j < CW; ++j) acc[i][j] = 0.f;

  #pragma unroll 4
  for (int k = 0; k < K; ++k) {
    float wv[CW];
    if constexpr (CW == 4)
      *reinterpret_cast<float4*>(&wv[0]) = *reinterpret_cast<const float4*>(&B[(size_t)k * NCOLS + c0]);
    else
      *reinterpret_cast<float2*>(&wv[0]) = *reinterpret_cast<const float2*>(&B[(size_t)k * NCOLS + c0]);
    float xv[8];
    #pragma unroll
    for (int i = 0; i < 8; ++i) xv[i] = As[n0 + i][k];
    #pragma unroll
    for (int i = 0; i < 8; ++i)
      #pragma unroll
      for (int j = 0; j < CW; ++j)
        acc[i][j] = fmaf(xv[i], wv[j], acc[i][j]);
  }

  float alv[CW], arv[CW];
  if constexpr (CW == 4) {
    *reinterpret_cast<float4*>(&alv[0]) = *reinterpret_cast<const float4*>(&al[c0]);
    *reinterpret_cast<float4*>(&arv[0]) = *reinterpret_cast<const float4*>(&ar[c0]);
  } else {
    *reinterpret_cast<float2*>(&alv[0]) = *reinterpret_cast<const float2*>(&al[c0]);
    *reinterpret_cast<float2*>(&arv[0]) = *reinterpret_cast<const float2*>(&ar[c0]);
  }
  constexpr int GRP = F / CW;              // lanes per head group
  const int h = c0 / F;

  #pragma unroll
  for (int i = 0; i < 8; ++i) {
    const int m = m0 + n0 + i;
    if (m < M) {
      if constexpr (CW == 4) {
        ushort4 u;
        u.x = f2bf(acc[i][0]); u.y = f2bf(acc[i][1]);
        u.z = f2bf(acc[i][2]); u.w = f2bf(acc[i][3]);
        *reinterpret_cast<ushort4*>(&hb[(size_t)m * NCOLS + c0]) = u;
      } else {
        ushort2 u;
        u.x = f2bf(acc[i][0]); u.y = f2bf(acc[i][1]);
        *reinterpret_cast<ushort2*>(&hb[(size_t)m * NCOLS + c0]) = u;
      }
    }
    float pl = 0.f, pr = 0.f;
    #pragma unroll
    for (int j = 0; j < CW; ++j) {
      pl = fmaf(alv[j], acc[i][j], pl);
      pr = fmaf(arv[j], acc[i][j], pr);
    }
    #pragma unroll
    for (int off = 1; off < GRP; off <<= 1) {
      pl += __shfl_xor(pl, off);
      pr += __shfl_xor(pr, off);
    }
    if (((tid & 31) & (GRP - 1)) == 0 && m < M) {
      el[(size_t)m * H + h] = pl;
      er[(size_t)m * H + h] = pr;
    }
  }
}

// ---------------- CSR build (scan + place) ----------------
__global__ __launch_bounds__(256) void block_sum_kernel(const int* __restrict__ deg,
    int* __restrict__ partials, int N) {
  __shared__ int wsum[4];
  const int tid = threadIdx.x;
  const int base = blockIdx.x * 1024 + tid * 4;
  int s = 0;
  #pragma unroll
  for (int j = 0; j < 4; ++j) if (base + j < N) s += deg[base + j];
  #pragma unroll
  for (int off = 32; off >= 1; off >>= 1) s += __shfl_down(s, off);
  if ((tid & 63) == 0) wsum[tid >> 6] = s;
  __syncthreads();
  if (tid == 0) partials[blockIdx.x] = wsum[0] + wsum[1] + wsum[2] + wsum[3];
}

__global__ __launch_bounds__(64) void scan_partials_kernel(int* partials, int nb) {
  const int tid = threadIdx.x;
  int v = (tid < nb) ? partials[tid] : 0;
  int incl = v;
  #pragma unroll
  for (int off = 1; off < 64; off <<= 1) {
    const int t = __shfl_up(incl, off);
    if (tid >= off) incl += t;
  }
  if (tid < nb) partials[tid] = incl - v;   // exclusive
}

__global__ __launch_bounds__(256) void block_scan_kernel(const int* __restrict__ deg,
    const int* __restrict__ partials, int* __restrict__ row_ptr, int N, int E) {
  __shared__ int wtot[4];
  const int tid = threadIdx.x;
  const int lane = tid & 63, wid = tid >> 6;
  const int idx = blockIdx.x * 1024 + tid * 4;
  int v[4];
  #pragma unroll
  for (int j = 0; j < 4; ++j) v[j] = (idx + j < N) ? deg[idx + j] : 0;
  const int tsum = v[0] + v[1] + v[2] + v[3];
  int incl = tsum;
  #pragma unroll
  for (int off = 1; off < 64; off <<= 1) {
    const int t = __shfl_up(incl, off);
    if (lane >= off) incl += t;
  }
  if (lane == 63) wtot[wid] = incl;
  __syncthreads();
  int excl = partials[blockIdx.x] + incl - tsum;
  for (int w = 0; w < wid; ++w) excl += wtot[w];
  #pragma unroll
  for (int j = 0; j < 4; ++j) {
    if (idx + j < N) { row_ptr[idx + j] = excl; excl += v[j]; }
  }
  if (blockIdx.x == 0 && tid == 0) row_ptr[N] = E;
}

// atomic-free placement; csr entries are ushort (src ids < 65536)
__global__ __launch_bounds__(256) void place_kernel(const int* __restrict__ src,
    const int* __restrict__ dst, const int* __restrict__ row_ptr,
    const int* __restrict__ rank, unsigned short* __restrict__ csr_src, int E) {
  const int e = blockIdx.x * 256 + threadIdx.x;
  if (e < E) {
    csr_src[row_ptr[dst[e]] + rank[e]] = (unsigned short)src[e];
  }
}

// ------- fused aggregate: NPW dst nodes per wave, CPL=4, bf16 gather, 16-deep MLP -------
template<int H, int F, int NPW>
__global__ __launch_bounds__(256) void gat_agg(const int* __restrict__ row_ptr,
    const unsigned short* __restrict__ csr_src, const float* __restrict__ el,
    const float* __restrict__ er, const unsigned short* __restrict__ hb,
    const float* __restrict__ bias, float* __restrict__ out, int N) {
  constexpr int HF = H * F;
  constexpr int LPN = 64 / NPW;            // lanes per node: 32 (L1) / 16 (L2)
  constexpr int CPL = HF / LPN;            // 4 in both layers
  static_assert(CPL == 4, "CPL must be 4");
  const int wid = threadIdx.x >> 6;
  const int lane = threadIdx.x & 63;
  const int g = lane / LPN;
  const int gl = lane % LPN;
  const int d = (blockIdx.x * 4 + wid) * NPW + g;
  if (d >= N) return;
  const int c0 = gl * CPL;
  const int h = c0 / F;
  const float erd = er[(size_t)d * H + h];
  const int beg = row_ptr[d], end = row_ptr[d + 1];
  float a0 = 0.f, a1 = 0.f, a2 = 0.f, a3 = 0.f, denom = 0.f;
  int i = beg;

  for (; i + 16 <= end; i += 16) {
    int s[16];
    #pragma unroll
    for (int j = 0; j < 16; ++j) s[j] = csr_src[i + j];
    float ee[16];
    #pragma unroll
    for (int j = 0; j < 16; ++j) ee[j] = el[(size_t)s[j] * H + h];
    ushort4 u[16];
    #pragma unroll
    for (int j = 0; j < 16; ++j)
      u[j] = *reinterpret_cast<const ushort4*>(&hb[(size_t)s[j] * HF + c0]);
    #pragma unroll
    for (int j = 0; j < 16; ++j) {
      float t = ee[j] + erd;
      t = fmaxf(t, NEG_SLOPE * t);
      const float x = __expf(t);
      denom += x;
      a0 = fmaf(x, bf2f(u[j].x), a0); a1 = fmaf(x, bf2f(u[j].y), a1);
      a2 = fmaf(x, bf2f(u[j].z), a2); a3 = fmaf(x, bf2f(u[j].w), a3);
    }
  }
  for (; i + 8 <= end; i += 8) {
    int s[8];
    #pragma unroll
    for (int j = 0; j < 8; ++j) s[j] = csr_src[i + j];
    float ee[8];
    #pragma unroll
    for (int j = 0; j < 8; ++j) ee[j] = el[(size_t)s[j] * H + h];
    ushort4 u[8];
    #pragma unroll
    for (int j = 0; j < 8; ++j)
      u[j] = *reinterpret_cast<const ushort4*>(&hb[(size_t)s[j] * HF + c0]);
    #pragma unroll
    for (int j = 0; j < 8; ++j) {
      float t = ee[j] + erd;
      t = fmaxf(t, NEG_SLOPE * t);
      const float x = __expf(t);
      denom += x;
      a0 = fmaf(x, bf2f(u[j].x), a0); a1 = fmaf(x, bf2f(u[j].y), a1);
      a2 = fmaf(x, bf2f(u[j].z), a2); a3 = fmaf(x, bf2f(u[j].w), a3);
    }
  }
  for (; i + 4 <= end; i += 4) {
    int s[4];
    #pragma unroll
    for (int j = 0; j < 4; ++j) s[j] = csr_src[i + j];
    float ee[4];
    #pragma unroll
    for (int j = 0; j < 4; ++j) ee[j] = el[(size_t)s[j] * H + h];
    ushort4 u[4];
    #pragma unroll
    for (int j = 0; j < 4; ++j)
      u[j] = *reinterpret_cast<const ushort4*>(&hb[(size_t)s[j] * HF + c0]);
    #pragma unroll
    for (int j = 0; j < 4; ++j) {
      float t = ee[j] + erd;
      t = fmaxf(t, NEG_SLOPE * t);
      const float x = __expf(t);
      denom += x;
      a0 = fmaf(x, bf2f(u[j].x), a0); a1 = fmaf(x, bf2f(u[j].y), a1);
      a2 = fmaf(x, bf2f(u[j].z), a2); a3 = fmaf(x, bf2f(u[j].w), a3);
    }
  }
  for (; i < end; ++i) {
    const int s = csr_src[i];
    float t = el[(size_t)s * H + h] + erd;
    t = fmaxf(t, NEG_SLOPE * t);
    const float x = __expf(t);
    denom += x;
    const ushort4 u = *reinterpret_cast<const ushort4*>(&hb[(size_t)s * HF + c0]);
    a0 = fmaf(x, bf2f(u.x), a0); a1 = fmaf(x, bf2f(u.y), a1);
    a2 = fmaf(x, bf2f(u.z), a2); a3 = fmaf(x, bf2f(u.w), a3);
  }

  const float inv = denom > 0.f ? 1.f / denom : 0.f;   // deg==0 -> out = bias
  const float4 bv = *reinterpret_cast<const float4*>(&bias[c0]);
  float4 o;
  o.x = bv.x + a0 * inv; o.y = bv.y + a1 * inv;
  o.z = bv.z + a2 * inv; o.w = bv.w + a3 * inv;
  *reinterpret_cast<float4*>(&out[(size_t)d * HF + c0]) = o;
}

extern "C" void kernel_launch(void* const* d_in, const int* in_sizes, int n_in,
                              void* d_out, int out_size, void* d_ws, size_t ws_size,
                              hipStream_t stream) {
  const float* x   = (const float*)d_in[0];
  const float* W1  = (const float*)d_in[1];
  const float* al1 = (const float*)d_in[2];
  const float* ar1 = (const float*)d_in[3];
  const float* b1  = (const float*)d_in[4];
  const float* W2  = (const float*)d_in[5];
  const float* al2 = (const float*)d_in[6];
  const float* ar2 = (const float*)d_in[7];
  const float* b2  = (const float*)d_in[8];
  const int* src   = (const int*)d_in[9];
  const int* dst   = (const int*)d_in[10];
  const int N = in_sizes[0] / 128;
  const int E = in_sizes[9];
  float* out = (float*)d_out;

  // workspace layout
  float* ws   = (float*)d_ws;
  float* out1 = ws;                          // N*128 f32
  float* el1  = out1 + (size_t)N * 128;      // N*4
  float* er1  = el1 + (size_t)N * 4;         // N*4
  float* el2  = er1 + (size_t)N * 4;         // N
  float* er2  = el2 + N;                     // N
  int* deg     = (int*)(er2 + N);            // N
  int* row_ptr = deg + N;                    // N+1
  int* rank    = row_ptr + N + 1;            // E
  unsigned short* csr_src = (unsigned short*)(rank + E);   // E (ushort)
  int* partials = (int*)(csr_src + ((E + 1) & ~1));        // ~N/1024+1
  unsigned short* hb1 = (unsigned short*)(partials + 64);  // N*128 bf16
  unsigned short* hb2 = hb1 + (size_t)N * 128;             // N*64 bf16

  const dim3 blk(256);
  const int nb = (N + 1023) / 1024;
  const int gemmBlocks = (N + 63) / 64;
  const int rankBlocks = (E + 255) / 256;

  // ---- deg zero, then layer-1 GEMM fused with CSR rank pass ----
  hipMemsetAsync(deg, 0, (size_t)N * sizeof(int), stream);
  gemm_eler_rank<128, 4><<<dim3(gemmBlocks + rankBlocks), blk, 0, stream>>>(
      x, W1, al1, ar1, hb1, el1, er1, N, gemmBlocks, dst, deg, rank, E);

  // ---- CSR scan + place ----
  block_sum_kernel<<<dim3(nb), blk, 0, stream>>>(deg, partials, N);
  scan_partials_kernel<<<dim3(1), dim3(64), 0, stream>>>(partials, nb);
  block_scan_kernel<<<dim3(nb), blk, 0, stream>>>(deg, partials, row_ptr, N, E);
  place_kernel<<<dim3(rankBlocks), blk, 0, stream>>>(src, dst, row_ptr, rank, csr_src, E);

  // ---- layer 1 aggregate: 2 nodes/wave ----
  gat_agg<4, 32, 2><<<dim3((N + 7) / 8), blk, 0, stream>>>(row_ptr, csr_src, el1, er1, hb1, b1, out1, N);

  // ---- layer 2: GEMM (no rank blocks) + aggregate: 4 nodes/wave ----
  gemm_eler_rank<64, 1><<<dim3(gemmBlocks), blk, 0, stream>>>(
      out1, W2, al2, ar2, hb2, el2, er2, N, gemmBlocks, dst, deg, rank, 0);
  gat_agg<1, 64, 4><<<dim3((N + 15) / 16), blk, 0, stream>>>(row_ptr, csr_src, el2, er2, hb2, b2, out, N);
}